// Round 1
// baseline (91.557 us; speedup 1.0000x reference)
//
#include <hip/hip_runtime.h>
#include <stdint.h>

#define DROI   12544
#define BIMG   16
#define NDET   128
#define NHID   128
#define SPLITK 14
#define KCHUNK 896      // SPLITK*KCHUNK = 12544
#define NTILES 14       // KCHUNK/64

typedef __bf16 bf16x8 __attribute__((ext_vector_type(8)));
typedef float  f32x4  __attribute__((ext_vector_type(4)));

// ---------------- ws layout (bytes) ----------------
#define OFF_WT    0UL
#define SZ_WT     ((unsigned long)NHID * DROI * 2)                 // 3,211,264
#define OFF_PART  (OFF_WT + SZ_WT)
#define SZ_PART   ((unsigned long)SPLITK * BIMG * 2 * 16384 * 4)   // 29,360,128
#define OFF_FIN   (OFF_PART + SZ_PART)
#define SZ_FIN    ((unsigned long)BIMG * 2 * 16384 * 4)            // 2,097,152
#define OFF_AH    (OFF_FIN + SZ_FIN)
#define SZ_AH     ((unsigned long)BIMG * 16384 * 2)                // 524,288
#define OFF_H1    (OFF_AH + SZ_AH)
#define OFF_T     (OFF_H1 + SZ_AH)

// ---------------- helpers ----------------
__device__ __forceinline__ unsigned pk2(float a, float b){
  unsigned ua = __float_as_uint(a), ub = __float_as_uint(b);
  ua = (ua + 0x7fffu + ((ua >> 16) & 1u)) >> 16;
  ub = (ub + 0x7fffu + ((ub >> 16) & 1u)) >> 16;
  return ua | (ub << 16);
}
__device__ __forceinline__ unsigned short bf1(float a){
  unsigned ua = __float_as_uint(a);
  return (unsigned short)((ua + 0x7fffu + ((ua >> 16) & 1u)) >> 16);
}
__device__ __forceinline__ f32x4 mfma16(bf16x8 a, bf16x8 b, f32x4 c){
  return __builtin_amdgcn_mfma_f32_16x16x32_bf16(a, b, c, 0, 0, 0);
}
__device__ __forceinline__ void gl_lds16(const void* g, void* l){
  __builtin_amdgcn_global_load_lds(
      (const __attribute__((address_space(1))) unsigned int*)g,
      (__attribute__((address_space(3))) unsigned int*)l, 16, 0, 0);
}
// 128-byte-row tile (128 rows x 64 bf16), XOR-swizzled (G4)
__device__ __forceinline__ bf16x8 ldfrag128(const short* base, int row, int bo){
  const char* p = (const char*)base + row * 128 + (bo ^ ((row & 7) << 4));
  return *(const bf16x8*)p;
}
// 256-byte-row tile (128 rows x 128 bf16), XOR-swizzled
__device__ __forceinline__ bf16x8 ldfrag256(const short* base, int row, int bo){
  const char* p = (const char*)base + row * 256 + (bo ^ ((row & 7) << 4));
  return *(const bf16x8*)p;
}

// ---------------- K0: W1[:12544][:] -> Wt bf16 [128][12544] ----------------
__global__ __launch_bounds__(256) void k0_wt(const float* __restrict__ W1,
                                             unsigned short* __restrict__ Wt){
  __shared__ float tile[64][133];
  const int t  = threadIdx.x;
  const int k0 = blockIdx.x * 64;
  const int r0 = t >> 5;
  const int c4 = (t & 31) * 4;
#pragma unroll
  for (int i = 0; i < 8; ++i){
    int r = r0 + i * 8;
    float4 v = *(const float4*)(W1 + (long)(k0 + r) * NHID + c4);
    tile[r][c4+0] = v.x; tile[r][c4+1] = v.y; tile[r][c4+2] = v.z; tile[r][c4+3] = v.w;
  }
  __syncthreads();
  const int h  = t >> 1;
  const int kc = (t & 1) * 32;
  unsigned* dst = (unsigned*)(Wt + (long)h * DROI + k0 + kc);
#pragma unroll
  for (int kk = 0; kk < 32; kk += 2)
    dst[kk >> 1] = pk2(tile[kc + kk][h], tile[kc + kk + 1][h]);
}

// ---------------- K1: fused Gram + fv@W1 (split-K, bf16 MFMA) ----------------
__global__ __launch_bounds__(256, 1) void k1_main(const float* __restrict__ fv,
    const unsigned short* __restrict__ Wt, float* __restrict__ part){
  __shared__ __align__(16) short lsA[2][8192];  // fv tile bf16, 16KB each
  __shared__ __align__(16) short lsB[2][8192];  // Wt tile bf16
  const int tid  = threadIdx.x;
  const int wave = tid >> 6, lane = tid & 63;
  const int s = blockIdx.x, b = blockIdx.y;
  const int kbase = s * KCHUNK;

  f32x4 gacc[2][8], wacc[2][8];
  {
    f32x4 z = {0.f, 0.f, 0.f, 0.f};
#pragma unroll
    for (int r = 0; r < 2; ++r)
#pragma unroll
      for (int c = 0; c < 8; ++c){ gacc[r][c] = z; wacc[r][c] = z; }
  }

  const int sr  = tid >> 1;          // staging row 0..127
  const int skp = (tid & 1) * 32;    // staging k offset within tile
  const float* fvp = fv + (long)(b * NDET + sr) * DROI + kbase + skp;
  const int hh  = lane >> 3;
  const int seg = (lane & 7) ^ hh;   // pre-swizzled source segment for gl_lds

  float4 stg[8];
#pragma unroll
  for (int i = 0; i < 8; ++i) stg[i] = *(const float4*)(fvp + i * 4);
#pragma unroll
  for (int j = 0; j < 4; ++j){
    int call = wave * 4 + j;
    int h = call * 8 + hh;
    const char* g = (const char*)Wt + (long)h * (DROI * 2) + (long)kbase * 2 + seg * 16;
    gl_lds16(g, (char*)lsB[0] + call * 1024);
  }
  {
    char* basep = (char*)lsA[0];
#pragma unroll
    for (int i = 0; i < 4; ++i){
      uint4 w;
      w.x = pk2(stg[2*i].x,   stg[2*i].y);
      w.y = pk2(stg[2*i].z,   stg[2*i].w);
      w.z = pk2(stg[2*i+1].x, stg[2*i+1].y);
      w.w = pk2(stg[2*i+1].z, stg[2*i+1].w);
      int bo = skp * 2 + i * 16;
      *(uint4*)(basep + sr * 128 + (bo ^ ((sr & 7) << 4))) = w;
    }
  }
  __syncthreads();

  int buf = 0;
  for (int t = 0; t < NTILES; ++t){
    const int nt = t + 1;
    if (nt < NTILES){
      const float* fp = fvp + nt * 64;
#pragma unroll
      for (int i = 0; i < 8; ++i) stg[i] = *(const float4*)(fp + i * 4);
#pragma unroll
      for (int j = 0; j < 4; ++j){
        int call = wave * 4 + j;
        int h = call * 8 + hh;
        const char* g = (const char*)Wt + (long)h * (DROI * 2)
                      + (long)(kbase + nt * 64) * 2 + seg * 16;
        gl_lds16(g, (char*)lsB[buf ^ 1] + call * 1024);
      }
    }
    const short* A  = lsA[buf];
    const short* Bw = lsB[buf];
#pragma unroll
    for (int kk = 0; kk < 2; ++kk){
      const int bo = kk * 64 + (lane >> 4) * 16;
      bf16x8 a0 = ldfrag128(A, (wave * 2 + 0) * 16 + (lane & 15), bo);
      bf16x8 a1 = ldfrag128(A, (wave * 2 + 1) * 16 + (lane & 15), bo);
#pragma unroll
      for (int cb = 0; cb < 8; ++cb){
        bf16x8 fb = ldfrag128(A,  cb * 16 + (lane & 15), bo);
        bf16x8 wb = ldfrag128(Bw, cb * 16 + (lane & 15), bo);
        gacc[0][cb] = mfma16(a0, fb, gacc[0][cb]);
        gacc[1][cb] = mfma16(a1, fb, gacc[1][cb]);
        wacc[0][cb] = mfma16(a0, wb, wacc[0][cb]);
        wacc[1][cb] = mfma16(a1, wb, wacc[1][cb]);
      }
    }
    if (nt < NTILES){
      char* basep = (char*)lsA[buf ^ 1];
#pragma unroll
      for (int i = 0; i < 4; ++i){
        uint4 w;
        w.x = pk2(stg[2*i].x,   stg[2*i].y);
        w.y = pk2(stg[2*i].z,   stg[2*i].w);
        w.z = pk2(stg[2*i+1].x, stg[2*i+1].y);
        w.w = pk2(stg[2*i+1].z, stg[2*i+1].w);
        int bo = skp * 2 + i * 16;
        *(uint4*)(basep + sr * 128 + (bo ^ ((sr & 7) << 4))) = w;
      }
    }
    __syncthreads();
    buf ^= 1;
  }

  float* pg = part + ((long)s * 32 + b * 2 + 0) * 16384;
  float* pw = part + ((long)s * 32 + b * 2 + 1) * 16384;
#pragma unroll
  for (int rb = 0; rb < 2; ++rb){
    const int R0 = wave * 32 + rb * 16 + (lane >> 4) * 4;
    const int C  = lane & 15;
#pragma unroll
    for (int cb = 0; cb < 8; ++cb){
#pragma unroll
      for (int i = 0; i < 4; ++i){
        pg[(R0 + i) * 128 + cb * 16 + C] = gacc[rb][cb][i];
        pw[(R0 + i) * 128 + cb * 16 + C] = wacc[rb][cb][i];
      }
    }
  }
}

// ---------------- KR: split-K reduction ----------------
__global__ __launch_bounds__(256) void k_reduce(const float* __restrict__ part,
                                                float* __restrict__ fin){
  const int e = blockIdx.x * 256 + threadIdx.x;   // 0..524287
  float s = 0.f;
#pragma unroll
  for (int k = 0; k < SPLITK; ++k) s += part[(long)k * 524288 + e];
  fin[e] = s;
}

// ---------------- K2a: adjacency + H1 = relu(Ah @ (x@W1) + b1) ----------------
__global__ __launch_bounds__(256, 1) void k2a(const float* __restrict__ fin,
    const float* __restrict__ ctr, const float* __restrict__ W1,
    const float* __restrict__ b1,
    unsigned short* __restrict__ AhWs, unsigned short* __restrict__ H1Ws){
  __shared__ __align__(16) short Ah[16384];   // 32KB bf16, row-major, swizzled
  __shared__ __align__(16) short Yt[16384];   // 32KB bf16, Y^T, swizzled
  const int b   = blockIdx.x;
  const int tid = threadIdx.x;
  const float* G = fin + (long)b * 32768;
  const float* Y = G + 16384;
  float* smallf = (float*)Yt;                 // [0..127] invn, [128..255] dinv (temp)

  if (tid < 128){
    float g = G[tid * 128 + tid];
    smallf[tid] = 1.0f / fmaxf(sqrtf(g), 1e-12f);
  }
  __syncthreads();

  const int   i   = tid >> 1;
  const int   jb  = (tid & 1) * 64;
  const float invni = smallf[i];
  const float cxi = ctr[(b * 128 + i) * 2 + 0];
  const float cyi = ctr[(b * 128 + i) * 2 + 1];
  unsigned m0 = 0, m1 = 0;
  int degloc = 0;
  for (int j4 = 0; j4 < 64; j4 += 4){
    float4 g4 = *(const float4*)(G + i * 128 + jb + j4);
    float gg[4] = {g4.x, g4.y, g4.z, g4.w};
#pragma unroll
    for (int u = 0; u < 4; ++u){
      int j = jb + j4 + u;
      float cs = gg[u] * invni * smallf[j];
      float dx = cxi - ctr[(b * 128 + j) * 2 + 0];
      float dy = cyi - ctr[(b * 128 + j) * 2 + 1];
      float d2 = dx * dx + dy * dy;
      if (d2 < 2500.0f || cs > 0.8f){
        int bp = j4 + u;
        if (bp < 32) m0 |= (1u << bp); else m1 |= (1u << (bp - 32));
        ++degloc;
      }
    }
  }
  if (i >= jb && i < jb + 64) ++degloc;       // PyG self-loop (+eye)
  int degfull = degloc + __shfl_xor(degloc, 1);
  if ((tid & 1) == 0) smallf[128 + i] = rsqrtf((float)degfull);
  __syncthreads();
  const float dinvi = smallf[128 + i];
  unsigned* wsrow = (unsigned*)(AhWs + (long)b * 16384 + i * 128 + jb);
  char* AhB = (char*)Ah;
  for (int jp = 0; jp < 64; jp += 2){
    int j0 = jb + jp, j1 = j0 + 1;
    float a0 = (((jp   < 32) ? ((m0 >> jp)        & 1u) : ((m1 >> (jp - 32))     & 1u)) ? 1.f : 0.f);
    float a1 = (((jp+1 < 32) ? ((m0 >> (jp + 1))  & 1u) : ((m1 >> (jp + 1 - 32)) & 1u)) ? 1.f : 0.f);
    if (i == j0) a0 += 1.f;
    if (i == j1) a1 += 1.f;
    float v0 = dinvi * a0 * smallf[128 + j0];
    float v1 = dinvi * a1 * smallf[128 + j1];
    unsigned pk = pk2(v0, v1);
    int bo = j0 * 2;
    *(unsigned*)(AhB + i * 256 + (bo ^ ((i & 7) << 4))) = pk;
    wsrow[jp >> 1] = pk;
  }
  __syncthreads();   // all smallf reads done before Yt overwrite

  // stage Yt[c][k] = Y[k][c] + ctr-part (x@W1 tail), bf16 swizzled
  const int c     = tid & 127;
  const int khalf = tid >> 7;
  const float w1a = W1[(long)12544 * NHID + c];
  const float w1b = W1[(long)12545 * NHID + c];
  char* YtB = (char*)Yt;
  for (int k8 = khalf * 64; k8 < khalf * 64 + 64; k8 += 8){
    float f[8];
#pragma unroll
    for (int u = 0; u < 8; ++u){
      int k = k8 + u;
      f[u] = Y[k * 128 + c] + ctr[(b*128 + k)*2 + 0] * w1a + ctr[(b*128 + k)*2 + 1] * w1b;
    }
    uint4 w;
    w.x = pk2(f[0], f[1]); w.y = pk2(f[2], f[3]);
    w.z = pk2(f[4], f[5]); w.w = pk2(f[6], f[7]);
    int bo = k8 * 2;
    *(uint4*)(YtB + c * 256 + (bo ^ ((c & 7) << 4))) = w;
  }
  __syncthreads();

  const int wave = tid >> 6, lane = tid & 63;
  f32x4 acc[2][8];
  {
    f32x4 z = {0.f, 0.f, 0.f, 0.f};
#pragma unroll
    for (int r = 0; r < 2; ++r)
#pragma unroll
      for (int cc = 0; cc < 8; ++cc) acc[r][cc] = z;
  }
#pragma unroll
  for (int ks = 0; ks < 4; ++ks){
    const int bo = ks * 64 + (lane >> 4) * 16;
    bf16x8 a0 = ldfrag256(Ah, (wave*2+0)*16 + (lane & 15), bo);
    bf16x8 a1 = ldfrag256(Ah, (wave*2+1)*16 + (lane & 15), bo);
#pragma unroll
    for (int cb = 0; cb < 8; ++cb){
      bf16x8 bb = ldfrag256(Yt, cb*16 + (lane & 15), bo);
      acc[0][cb] = mfma16(a0, bb, acc[0][cb]);
      acc[1][cb] = mfma16(a1, bb, acc[1][cb]);
    }
  }
#pragma unroll
  for (int rb = 0; rb < 2; ++rb){
    const int R0 = wave*32 + rb*16 + (lane >> 4)*4;
#pragma unroll
    for (int cb = 0; cb < 8; ++cb){
      const int C = cb*16 + (lane & 15);
      const float bb1 = b1[C];
#pragma unroll
      for (int u = 0; u < 4; ++u){
        float v = fmaxf(acc[rb][cb][u] + bb1, 0.f);
        H1Ws[(long)b*16384 + (R0+u)*128 + C] = bf1(v);
      }
    }
  }
}

// ---------------- K2b: T = H1 @ W2 ----------------
__global__ __launch_bounds__(256, 1) void k2b(const unsigned short* __restrict__ H1Ws,
    const float* __restrict__ W2, unsigned short* __restrict__ TWs){
  __shared__ __align__(16) short H1[16384];
  __shared__ __align__(16) short W2t[16384];
  const int b   = blockIdx.x;
  const int tid = threadIdx.x;
  const int wave = tid >> 6, lane = tid & 63;
  {
    const char* src = (const char*)(H1Ws + (long)b * 16384);
#pragma unroll
    for (int j = 0; j < 8; ++j){
      int call = wave * 8 + j;
      int h  = call * 4 + (lane >> 4);
      int bo = (lane & 15) * 16;
      gl_lds16(src + h * 256 + (bo ^ ((h & 7) << 4)), (char*)H1 + call * 1024);
    }
  }
  const int c     = tid & 127;
  const int khalf = tid >> 7;
  char* WB = (char*)W2t;
  for (int k8 = khalf * 64; k8 < khalf * 64 + 64; k8 += 8){
    float f[8];
#pragma unroll
    for (int u = 0; u < 8; ++u) f[u] = W2[(k8 + u) * 128 + c];
    uint4 w;
    w.x = pk2(f[0], f[1]); w.y = pk2(f[2], f[3]);
    w.z = pk2(f[4], f[5]); w.w = pk2(f[6], f[7]);
    int bo = k8 * 2;
    *(uint4*)(WB + c * 256 + (bo ^ ((c & 7) << 4))) = w;
  }
  __syncthreads();
  f32x4 acc[2][8];
  {
    f32x4 z = {0.f, 0.f, 0.f, 0.f};
#pragma unroll
    for (int r = 0; r < 2; ++r)
#pragma unroll
      for (int cc = 0; cc < 8; ++cc) acc[r][cc] = z;
  }
#pragma unroll
  for (int ks = 0; ks < 4; ++ks){
    const int bo = ks * 64 + (lane >> 4) * 16;
    bf16x8 a0 = ldfrag256(H1, (wave*2+0)*16 + (lane & 15), bo);
    bf16x8 a1 = ldfrag256(H1, (wave*2+1)*16 + (lane & 15), bo);
#pragma unroll
    for (int cb = 0; cb < 8; ++cb){
      bf16x8 bb = ldfrag256(W2t, cb*16 + (lane & 15), bo);
      acc[0][cb] = mfma16(a0, bb, acc[0][cb]);
      acc[1][cb] = mfma16(a1, bb, acc[1][cb]);
    }
  }
#pragma unroll
  for (int rb = 0; rb < 2; ++rb){
    const int R0 = wave*32 + rb*16 + (lane >> 4)*4;
#pragma unroll
    for (int cb = 0; cb < 8; ++cb){
      const int C = cb*16 + (lane & 15);
#pragma unroll
      for (int u = 0; u < 4; ++u)
        TWs[(long)b*16384 + (R0+u)*128 + C] = bf1(acc[rb][cb][u]);
    }
  }
}

// ---------------- K2c: C2 = Ah @ T; relu(+b2); mean-pool; logits ----------------
__global__ __launch_bounds__(256, 1) void k2c(const unsigned short* __restrict__ AhWs,
    const unsigned short* __restrict__ TWs, const float* __restrict__ b2,
    const float* __restrict__ Wc, const float* __restrict__ bc,
    float* __restrict__ out){
  __shared__ __align__(16) short Ah[16384];
  __shared__ __align__(16) short Tt[16384];
  const int b   = blockIdx.x;
  const int tid = threadIdx.x;
  const int wave = tid >> 6, lane = tid & 63;
  {
    const char* src = (const char*)(AhWs + (long)b * 16384);
#pragma unroll
    for (int j = 0; j < 8; ++j){
      int call = wave * 8 + j;
      int h  = call * 4 + (lane >> 4);
      int bo = (lane & 15) * 16;
      gl_lds16(src + h * 256 + (bo ^ ((h & 7) << 4)), (char*)Ah + call * 1024);
    }
  }
  const int c     = tid & 127;
  const int khalf = tid >> 7;
  const unsigned short* Tsrc = TWs + (long)b * 16384;
  char* TB = (char*)Tt;
  for (int k8 = khalf * 64; k8 < khalf * 64 + 64; k8 += 8){
    unsigned short f[8];
#pragma unroll
    for (int u = 0; u < 8; ++u) f[u] = Tsrc[(k8 + u) * 128 + c];
    uint4 w;
    w.x = (unsigned)f[0] | ((unsigned)f[1] << 16);
    w.y = (unsigned)f[2] | ((unsigned)f[3] << 16);
    w.z = (unsigned)f[4] | ((unsigned)f[5] << 16);
    w.w = (unsigned)f[6] | ((unsigned)f[7] << 16);
    int bo = k8 * 2;
    *(uint4*)(TB + c * 256 + (bo ^ ((c & 7) << 4))) = w;
  }
  __syncthreads();
  f32x4 acc[2][8];
  {
    f32x4 z = {0.f, 0.f, 0.f, 0.f};
#pragma unroll
    for (int r = 0; r < 2; ++r)
#pragma unroll
      for (int cc = 0; cc < 8; ++cc) acc[r][cc] = z;
  }
#pragma unroll
  for (int ks = 0; ks < 4; ++ks){
    const int bo = ks * 64 + (lane >> 4) * 16;
    bf16x8 a0 = ldfrag256(Ah, (wave*2+0)*16 + (lane & 15), bo);
    bf16x8 a1 = ldfrag256(Ah, (wave*2+1)*16 + (lane & 15), bo);
#pragma unroll
    for (int cb = 0; cb < 8; ++cb){
      bf16x8 bb = ldfrag256(Tt, cb*16 + (lane & 15), bo);
      acc[0][cb] = mfma16(a0, bb, acc[0][cb]);
      acc[1][cb] = mfma16(a1, bb, acc[1][cb]);
    }
  }
  float colp[8];
#pragma unroll
  for (int cb = 0; cb < 8; ++cb){
    const int C = cb*16 + (lane & 15);
    const float bb2 = b2[C];
    float sum = 0.f;
#pragma unroll
    for (int rb = 0; rb < 2; ++rb)
#pragma unroll
      for (int u = 0; u < 4; ++u)
        sum += fmaxf(acc[rb][cb][u] + bb2, 0.f);
    colp[cb] = sum;
  }
#pragma unroll
  for (int cb = 0; cb < 8; ++cb){
    float v = colp[cb];
    v += __shfl_xor(v, 16);
    v += __shfl_xor(v, 32);
    colp[cb] = v;
  }
  __syncthreads();                    // GEMM reads of Ah/Tt done
  float* hgp = (float*)Ah;            // [4][128]
  if ((lane >> 4) == 0){
#pragma unroll
    for (int cb = 0; cb < 8; ++cb)
      hgp[wave * 128 + cb * 16 + lane] = colp[cb];
  }
  __syncthreads();
  float* hg = hgp + 512;
  if (tid < 128)
    hg[tid] = (hgp[tid] + hgp[128 + tid] + hgp[256 + tid] + hgp[384 + tid]) * (1.0f / 128.0f);
  __syncthreads();
  if (tid < 22){
    float a2 = bc[tid];
    for (int h = 0; h < 128; ++h) a2 += hg[h] * Wc[h * 22 + tid];
    out[b * 22 + tid] = a2;
  }
}

// ---------------- launch ----------------
extern "C" void kernel_launch(void* const* d_in, const int* in_sizes, int n_in,
                              void* d_out, int out_size, void* d_ws, size_t ws_size,
                              hipStream_t stream){
  (void)in_sizes; (void)n_in; (void)out_size; (void)ws_size;
  const float* fv  = (const float*)d_in[0];
  const float* ctr = (const float*)d_in[1];
  const float* W1  = (const float*)d_in[2];
  const float* b1  = (const float*)d_in[3];
  const float* W2  = (const float*)d_in[4];
  const float* b2  = (const float*)d_in[5];
  const float* Wc  = (const float*)d_in[6];
  const float* bc  = (const float*)d_in[7];
  char* ws = (char*)d_ws;
  unsigned short* Wt   = (unsigned short*)(ws + OFF_WT);
  float*          part = (float*)(ws + OFF_PART);
  float*          fin  = (float*)(ws + OFF_FIN);
  unsigned short* AhWs = (unsigned short*)(ws + OFF_AH);
  unsigned short* H1Ws = (unsigned short*)(ws + OFF_H1);
  unsigned short* TWs  = (unsigned short*)(ws + OFF_T);
  float* out = (float*)d_out;

  k0_wt   <<<dim3(DROI / 64),        dim3(256), 0, stream>>>(W1, Wt);
  k1_main <<<dim3(SPLITK, BIMG),     dim3(256), 0, stream>>>(fv, Wt, part);
  k_reduce<<<dim3(2048),             dim3(256), 0, stream>>>(part, fin);
  k2a     <<<dim3(BIMG),             dim3(256), 0, stream>>>(fin, ctr, W1, b1, AhWs, H1Ws);
  k2b     <<<dim3(BIMG),             dim3(256), 0, stream>>>(H1Ws, W2, TWs);
  k2c     <<<dim3(BIMG),             dim3(256), 0, stream>>>(AhWs, TWs, b2, Wc, bc, out);
}

// Round 2
// 70.974 us; speedup vs baseline: 1.2900x; 1.2900x over previous
//
#include <hip/hip_runtime.h>
#include <stdint.h>

#define DROI   12544
#define BIMG   16
#define NDET   128
#define NHID   128

typedef __bf16 bf16x8 __attribute__((ext_vector_type(8)));
typedef float  f32x4  __attribute__((ext_vector_type(4)));

// ---------------- helpers ----------------
__device__ __forceinline__ unsigned pk2(float a, float b){
  unsigned ua = __float_as_uint(a), ub = __float_as_uint(b);
  ua = (ua + 0x7fffu + ((ua >> 16) & 1u)) >> 16;
  ub = (ub + 0x7fffu + ((ub >> 16) & 1u)) >> 16;
  return ua | (ub << 16);
}
__device__ __forceinline__ unsigned short bf1(float a){
  unsigned ua = __float_as_uint(a);
  return (unsigned short)((ua + 0x7fffu + ((ua >> 16) & 1u)) >> 16);
}
__device__ __forceinline__ f32x4 mfma16(bf16x8 a, bf16x8 b, f32x4 c){
  return __builtin_amdgcn_mfma_f32_16x16x32_bf16(a, b, c, 0, 0, 0);
}
__device__ __forceinline__ void gl_lds16(const void* g, void* l){
  __builtin_amdgcn_global_load_lds(
      (const __attribute__((address_space(1))) unsigned int*)g,
      (__attribute__((address_space(3))) unsigned int*)l, 16, 0, 0);
}
// 128-byte-row tile (128 rows x 64 bf16), XOR-swizzled
__device__ __forceinline__ bf16x8 ldfrag128(const short* base, int row, int bo){
  const char* p = (const char*)base + row * 128 + (bo ^ ((row & 7) << 4));
  return *(const bf16x8*)p;
}
// 256-byte-row tile (128 rows x 128 bf16), XOR-swizzled
__device__ __forceinline__ bf16x8 ldfrag256(const short* base, int row, int bo){
  const char* p = (const char*)base + row * 256 + (bo ^ ((row & 7) << 4));
  return *(const bf16x8*)p;
}

// ---------------- K0: W1[:12544][:] -> Wt bf16 [128][12544] ----------------
__global__ __launch_bounds__(256) void k0_wt(const float* __restrict__ W1,
                                             unsigned short* __restrict__ Wt){
  __shared__ float tile[64][133];
  const int t  = threadIdx.x;
  const int k0 = blockIdx.x * 64;
  const int r0 = t >> 5;
  const int c4 = (t & 31) * 4;
#pragma unroll
  for (int i = 0; i < 8; ++i){
    int r = r0 + i * 8;
    float4 v = *(const float4*)(W1 + (long)(k0 + r) * NHID + c4);
    tile[r][c4+0] = v.x; tile[r][c4+1] = v.y; tile[r][c4+2] = v.z; tile[r][c4+3] = v.w;
  }
  __syncthreads();
  const int h  = t >> 1;
  const int kc = (t & 1) * 32;
  unsigned* dst = (unsigned*)(Wt + (long)h * DROI + k0 + kc);
#pragma unroll
  for (int kk = 0; kk < 32; kk += 2)
    dst[kk >> 1] = pk2(tile[kc + kk][h], tile[kc + kk + 1][h]);
}

// ---------------- K1: fused Gram + fv@W1 (split-K, wave role-split) --------
template<int SK>
__global__ __launch_bounds__(256, 2) void k1_main(const float* __restrict__ fv,
    const unsigned short* __restrict__ Wt, float* __restrict__ part){
  constexpr int KC = DROI / SK;   // K chunk per block
  constexpr int NT = KC / 64;     // 64-wide K tiles
  __shared__ __align__(16) short lsA[2][8192];  // fv tile bf16 (16KB each)
  __shared__ __align__(16) short lsB[2][8192];  // Wt tile bf16
  const int tid  = threadIdx.x;
  const int wave = tid >> 6, lane = tid & 63;
  const int s = blockIdx.x, b = blockIdx.y;
  const int kbase = s * KC;

  f32x4 acc[4][8];
  {
    f32x4 z = {0.f, 0.f, 0.f, 0.f};
#pragma unroll
    for (int m = 0; m < 4; ++m)
#pragma unroll
      for (int c = 0; c < 8; ++c) acc[m][c] = z;
  }

  // fv staging mapping: thread handles rows r0+16i, float cols colf..colf+3
  const int r0   = tid >> 4;          // 0..15
  const int colf = (tid & 15) * 4;    // 0..60
  const float* fvt = fv + (long)(b * NDET + r0) * DROI + kbase + colf;
  const int hh  = lane >> 3;
  const int seg = (lane & 7) ^ hh;    // pre-swizzled source segment for gl_lds

  float4 stg[8];
  // ---- prologue: tile 0 ----
#pragma unroll
  for (int j = 0; j < 4; ++j){
    int call = wave * 4 + j;
    int h = call * 8 + hh;
    const char* g = (const char*)Wt + (long)h * (DROI * 2) + (long)kbase * 2 + seg * 16;
    gl_lds16(g, (char*)lsB[0] + call * 1024);
  }
#pragma unroll
  for (int i = 0; i < 8; ++i) stg[i] = *(const float4*)(fvt + (long)i * 16 * DROI);
  {
    char* basep = (char*)lsA[0];
#pragma unroll
    for (int i = 0; i < 8; ++i){
      int r = r0 + i * 16;
      uint2 w; w.x = pk2(stg[i].x, stg[i].y); w.y = pk2(stg[i].z, stg[i].w);
      *(uint2*)(basep + r * 128 + ((colf * 2) ^ ((r & 7) << 4))) = w;
    }
  }
  __syncthreads();

  const int outw = wave >> 1;         // 0 = Gram, 1 = XW1
  const int mh   = wave & 1;          // M-half
  const int lq   = lane & 15;
  int buf = 0;
  for (int t = 0; t < NT; ++t){
    const int nt = t + 1;
    if (nt < NT){
#pragma unroll
      for (int j = 0; j < 4; ++j){
        int call = wave * 4 + j;
        int h = call * 8 + hh;
        const char* g = (const char*)Wt + (long)h * (DROI * 2)
                      + (long)(kbase + nt * 64) * 2 + seg * 16;
        gl_lds16(g, (char*)lsB[buf ^ 1] + call * 1024);
      }
      const float* fp = fvt + nt * 64;
#pragma unroll
      for (int i = 0; i < 8; ++i) stg[i] = *(const float4*)(fp + (long)i * 16 * DROI);
    }
    const short* A  = lsA[buf];
    const short* Bs = outw ? lsB[buf] : lsA[buf];
#pragma unroll
    for (int kk = 0; kk < 2; ++kk){
      const int bo = kk * 64 + (lane >> 4) * 16;
      bf16x8 am[4];
#pragma unroll
      for (int m = 0; m < 4; ++m)
        am[m] = ldfrag128(A, mh * 64 + m * 16 + lq, bo);
#pragma unroll
      for (int cb = 0; cb < 8; ++cb){
        bf16x8 bb = ldfrag128(Bs, cb * 16 + lq, bo);
#pragma unroll
        for (int m = 0; m < 4; ++m)
          acc[m][cb] = mfma16(am[m], bb, acc[m][cb]);
      }
    }
    if (nt < NT){
      char* basep = (char*)lsA[buf ^ 1];
#pragma unroll
      for (int i = 0; i < 8; ++i){
        int r = r0 + i * 16;
        uint2 w; w.x = pk2(stg[i].x, stg[i].y); w.y = pk2(stg[i].z, stg[i].w);
        *(uint2*)(basep + r * 128 + ((colf * 2) ^ ((r & 7) << 4))) = w;
      }
    }
    __syncthreads();
    buf ^= 1;
  }

  float* dst = part + ((long)s * 32 + b * 2 + outw) * 16384;
#pragma unroll
  for (int m = 0; m < 4; ++m){
    const int R0 = mh * 64 + m * 16 + (lane >> 4) * 4;
#pragma unroll
    for (int cb = 0; cb < 8; ++cb){
#pragma unroll
      for (int i = 0; i < 4; ++i)
        dst[(R0 + i) * 128 + cb * 16 + lq] = acc[m][cb][i];
    }
  }
}

// ---------------- KR: split-K reduction (float4) ----------------
template<int SK>
__global__ __launch_bounds__(256) void k_reduce(const float4* __restrict__ part4,
                                                float4* __restrict__ fin4){
  const int e = blockIdx.x * 256 + threadIdx.x;   // 0..131071
  float4 s = {0.f, 0.f, 0.f, 0.f};
#pragma unroll
  for (int k = 0; k < SK; ++k){
    float4 p = part4[(long)k * 131072 + e];
    s.x += p.x; s.y += p.y; s.z += p.z; s.w += p.w;
  }
  fin4[e] = s;
}

// ---------------- K2: fused adjacency + 3 GEMMs + pool + logits ------------
__global__ __launch_bounds__(256, 1) void k2f(const float* __restrict__ fin,
    const float* __restrict__ ctr, const float* __restrict__ W1,
    const float* __restrict__ b1, const float* __restrict__ W2,
    const float* __restrict__ b2, const float* __restrict__ Wc,
    const float* __restrict__ bc, float* __restrict__ out){
  __shared__ __align__(16) short Ah[16384];   // 32KB: normalized adjacency (persistent)
  __shared__ __align__(16) short Bu[16384];   // 32KB: Yt -> H1 -> Tt
  __shared__ __align__(16) short Cu[16384];   // 32KB: W2t -> pool scratch
  __shared__ float sm2[256];                  // [0..127] invn, [128..255] dinv
  const int b   = blockIdx.x;
  const int tid = threadIdx.x;
  const float* G = fin + (long)b * 32768;
  const float* Y = G + 16384;

  // (1) inverse norms from Gram diagonal
  if (tid < 128){
    float g = G[tid * 129];
    sm2[tid] = 1.0f / fmaxf(sqrtf(g), 1e-12f);
  }
  __syncthreads();

  // (2) adjacency masks + degrees
  const int   i   = tid >> 1;
  const int   jb  = (tid & 1) * 64;
  const float invni = sm2[i];
  const float cxi = ctr[(b * 128 + i) * 2 + 0];
  const float cyi = ctr[(b * 128 + i) * 2 + 1];
  unsigned m0 = 0, m1 = 0;
  int degloc = 0;
  for (int j4 = 0; j4 < 64; j4 += 4){
    float4 g4 = *(const float4*)(G + i * 128 + jb + j4);
    float gg[4] = {g4.x, g4.y, g4.z, g4.w};
#pragma unroll
    for (int u = 0; u < 4; ++u){
      int j = jb + j4 + u;
      float cs = gg[u] * invni * sm2[j];
      float dx = cxi - ctr[(b * 128 + j) * 2 + 0];
      float dy = cyi - ctr[(b * 128 + j) * 2 + 1];
      float d2 = dx * dx + dy * dy;
      if (d2 < 2500.0f || cs > 0.8f){
        int bp = j4 + u;
        if (bp < 32) m0 |= (1u << bp); else m1 |= (1u << (bp - 32));
        ++degloc;
      }
    }
  }
  if (i >= jb && i < jb + 64) ++degloc;       // self loop
  int degfull = degloc + __shfl_xor(degloc, 1);
  if ((tid & 1) == 0) sm2[128 + i] = rsqrtf((float)degfull);
  __syncthreads();

  // (3) write normalized adjacency into Ah (swizzled bf16)
  {
    const float dinvi = sm2[128 + i];
    char* AhB = (char*)Ah;
    for (int jp = 0; jp < 64; jp += 2){
      int j0 = jb + jp, j1 = j0 + 1;
      float a0 = (((jp   < 32) ? ((m0 >> jp)       & 1u) : ((m1 >> (jp - 32))     & 1u)) ? 1.f : 0.f);
      float a1 = (((jp+1 < 32) ? ((m0 >> (jp + 1)) & 1u) : ((m1 >> (jp + 1 - 32)) & 1u)) ? 1.f : 0.f);
      if (i == j0) a0 += 1.f;
      if (i == j1) a1 += 1.f;
      float v0 = dinvi * a0 * sm2[128 + j0];
      float v1 = dinvi * a1 * sm2[128 + j1];
      int bo = j0 * 2;
      *(unsigned*)(AhB + i * 256 + (bo ^ ((i & 7) << 4))) = pk2(v0, v1);
    }
  }

  const int c     = tid & 127;
  const int khalf = tid >> 7;
  // (4) stage W2t[c][k] into Cu
  {
    char* WB = (char*)Cu;
    for (int k8 = khalf * 64; k8 < khalf * 64 + 64; k8 += 8){
      float f[8];
#pragma unroll
      for (int u = 0; u < 8; ++u) f[u] = W2[(k8 + u) * 128 + c];
      uint4 w;
      w.x = pk2(f[0], f[1]); w.y = pk2(f[2], f[3]);
      w.z = pk2(f[4], f[5]); w.w = pk2(f[6], f[7]);
      int bo = k8 * 2;
      *(uint4*)(WB + c * 256 + (bo ^ ((c & 7) << 4))) = w;
    }
  }
  // (5) stage Yt[c][k] = Y[k][c] + ctr tail of x@W1, into Bu
  {
    const float w1a = W1[(long)12544 * NHID + c];
    const float w1b = W1[(long)12545 * NHID + c];
    char* YtB = (char*)Bu;
    for (int k8 = khalf * 64; k8 < khalf * 64 + 64; k8 += 8){
      float f[8];
#pragma unroll
      for (int u = 0; u < 8; ++u){
        int k = k8 + u;
        f[u] = Y[k * 128 + c] + ctr[(b*128 + k)*2 + 0] * w1a + ctr[(b*128 + k)*2 + 1] * w1b;
      }
      uint4 w;
      w.x = pk2(f[0], f[1]); w.y = pk2(f[2], f[3]);
      w.z = pk2(f[4], f[5]); w.w = pk2(f[6], f[7]);
      int bo = k8 * 2;
      *(uint4*)(YtB + c * 256 + (bo ^ ((c & 7) << 4))) = w;
    }
  }
  __syncthreads();

  const int wave = tid >> 6, lane = tid & 63;
  const int lq = lane & 15;
  f32x4 acc[2][8];
  f32x4 z4 = {0.f, 0.f, 0.f, 0.f};

  // (6) GEMM1: H1 = relu(Ah @ Yt + b1)
#pragma unroll
  for (int r = 0; r < 2; ++r)
#pragma unroll
    for (int cc = 0; cc < 8; ++cc) acc[r][cc] = z4;
#pragma unroll
  for (int ks = 0; ks < 4; ++ks){
    const int bo = ks * 64 + (lane >> 4) * 16;
    bf16x8 a0 = ldfrag256(Ah, (wave*2+0)*16 + lq, bo);
    bf16x8 a1 = ldfrag256(Ah, (wave*2+1)*16 + lq, bo);
#pragma unroll
    for (int cb = 0; cb < 8; ++cb){
      bf16x8 bb = ldfrag256(Bu, cb*16 + lq, bo);
      acc[0][cb] = mfma16(a0, bb, acc[0][cb]);
      acc[1][cb] = mfma16(a1, bb, acc[1][cb]);
    }
  }
  __syncthreads();   // all Yt reads done
  // (7) scatter H1 (bf16, swizzled) into Bu
  {
    char* BuB = (char*)Bu;
#pragma unroll
    for (int rb = 0; rb < 2; ++rb){
      const int R0 = wave*32 + rb*16 + (lane >> 4)*4;
#pragma unroll
      for (int cb = 0; cb < 8; ++cb){
        const int C = cb*16 + lq;
        const float bb1 = b1[C];
#pragma unroll
        for (int u = 0; u < 4; ++u){
          float v = fmaxf(acc[rb][cb][u] + bb1, 0.f);
          int row = R0 + u;
          *(unsigned short*)(BuB + row * 256 + ((C * 2) ^ ((row & 7) << 4))) = bf1(v);
        }
      }
    }
  }
  __syncthreads();

  // (8) GEMM2: T = H1 @ W2t
#pragma unroll
  for (int r = 0; r < 2; ++r)
#pragma unroll
    for (int cc = 0; cc < 8; ++cc) acc[r][cc] = z4;
#pragma unroll
  for (int ks = 0; ks < 4; ++ks){
    const int bo = ks * 64 + (lane >> 4) * 16;
    bf16x8 a0 = ldfrag256(Bu, (wave*2+0)*16 + lq, bo);
    bf16x8 a1 = ldfrag256(Bu, (wave*2+1)*16 + lq, bo);
#pragma unroll
    for (int cb = 0; cb < 8; ++cb){
      bf16x8 bb = ldfrag256(Cu, cb*16 + lq, bo);
      acc[0][cb] = mfma16(a0, bb, acc[0][cb]);
      acc[1][cb] = mfma16(a1, bb, acc[1][cb]);
    }
  }
  __syncthreads();   // all H1 reads done
  // (9) scatter T^T into Bu: Tt[c][k]
  {
    char* BuB = (char*)Bu;
#pragma unroll
    for (int rb = 0; rb < 2; ++rb){
      const int R0 = wave*32 + rb*16 + (lane >> 4)*4;
#pragma unroll
      for (int cb = 0; cb < 8; ++cb){
        const int C = cb*16 + lq;
#pragma unroll
        for (int u = 0; u < 4; ++u){
          int k = R0 + u;
          *(unsigned short*)(BuB + C * 256 + ((k * 2) ^ ((C & 7) << 4))) = bf1(acc[rb][cb][u]);
        }
      }
    }
  }
  __syncthreads();

  // (10) GEMM3: C2 = Ah @ Tt; relu(+b2); mean pool; logits
#pragma unroll
  for (int r = 0; r < 2; ++r)
#pragma unroll
    for (int cc = 0; cc < 8; ++cc) acc[r][cc] = z4;
#pragma unroll
  for (int ks = 0; ks < 4; ++ks){
    const int bo = ks * 64 + (lane >> 4) * 16;
    bf16x8 a0 = ldfrag256(Ah, (wave*2+0)*16 + lq, bo);
    bf16x8 a1 = ldfrag256(Ah, (wave*2+1)*16 + lq, bo);
#pragma unroll
    for (int cb = 0; cb < 8; ++cb){
      bf16x8 bb = ldfrag256(Bu, cb*16 + lq, bo);
      acc[0][cb] = mfma16(a0, bb, acc[0][cb]);
      acc[1][cb] = mfma16(a1, bb, acc[1][cb]);
    }
  }
  float colp[8];
#pragma unroll
  for (int cb = 0; cb < 8; ++cb){
    const int C = cb*16 + lq;
    const float bb2 = b2[C];
    float sum = 0.f;
#pragma unroll
    for (int rb = 0; rb < 2; ++rb)
#pragma unroll
      for (int u = 0; u < 4; ++u)
        sum += fmaxf(acc[rb][cb][u] + bb2, 0.f);
    colp[cb] = sum;
  }
#pragma unroll
  for (int cb = 0; cb < 8; ++cb){
    float v = colp[cb];
    v += __shfl_xor(v, 16);
    v += __shfl_xor(v, 32);
    colp[cb] = v;
  }
  __syncthreads();                    // GEMM reads done; Cu free
  float* hgp = (float*)Cu;            // [4][128]
  if ((lane >> 4) == 0){
#pragma unroll
    for (int cb = 0; cb < 8; ++cb)
      hgp[wave * 128 + cb * 16 + lane] = colp[cb];
  }
  __syncthreads();
  float* hg = hgp + 512;
  if (tid < 128)
    hg[tid] = (hgp[tid] + hgp[128 + tid] + hgp[256 + tid] + hgp[384 + tid]) * (1.0f / 128.0f);
  __syncthreads();
  if (tid < 22){
    float a2 = bc[tid];
    for (int h = 0; h < 128; ++h) a2 += hg[h] * Wc[h * 22 + tid];
    out[b * 22 + tid] = a2;
  }
}

// ---------------- launch ----------------
extern "C" void kernel_launch(void* const* d_in, const int* in_sizes, int n_in,
                              void* d_out, int out_size, void* d_ws, size_t ws_size,
                              hipStream_t stream){
  (void)in_sizes; (void)n_in; (void)out_size;
  const float* fv  = (const float*)d_in[0];
  const float* ctr = (const float*)d_in[1];
  const float* W1  = (const float*)d_in[2];
  const float* b1  = (const float*)d_in[3];
  const float* W2  = (const float*)d_in[4];
  const float* b2  = (const float*)d_in[5];
  const float* Wc  = (const float*)d_in[6];
  const float* bc  = (const float*)d_in[7];
  char* ws = (char*)d_ws;
  float* out = (float*)d_out;

  const unsigned long SZ_WT = (unsigned long)NHID * DROI * 2;     // 3,211,264
  const unsigned long SZ_FIN = (unsigned long)BIMG * 2 * 16384 * 4;

  // choose split-K by available scratch: 28 needs ~64 MB, 14 needs ~35 MB
  const unsigned long need28 = SZ_WT + 28UL * 2097152UL + SZ_FIN;
  const bool big = (ws_size >= need28);
  const int SK = big ? 28 : 14;

  unsigned short* Wt   = (unsigned short*)(ws);
  float*          part = (float*)(ws + SZ_WT);
  float*          fin  = (float*)(ws + SZ_WT + (unsigned long)SK * 2097152UL);

  k0_wt<<<dim3(DROI / 64), dim3(256), 0, stream>>>(W1, Wt);
  if (big){
    k1_main<28><<<dim3(28, BIMG), dim3(256), 0, stream>>>(fv, Wt, part);
    k_reduce<28><<<dim3(512), dim3(256), 0, stream>>>((const float4*)part, (float4*)fin);
  } else {
    k1_main<14><<<dim3(14, BIMG), dim3(256), 0, stream>>>(fv, Wt, part);
    k_reduce<14><<<dim3(512), dim3(256), 0, stream>>>((const float4*)part, (float4*)fin);
  }
  k2f<<<dim3(BIMG), dim3(256), 0, stream>>>(fin, ctr, W1, b1, W2, b2, Wc, bc, out);
}

// Round 3
// 65.351 us; speedup vs baseline: 1.4010x; 1.0860x over previous
//
#include <hip/hip_runtime.h>
#include <stdint.h>

#define DROI   12544
#define BIMG   16
#define NDET   128
#define NHID   128

typedef __bf16 bf16x8 __attribute__((ext_vector_type(8)));
typedef float  f32x4  __attribute__((ext_vector_type(4)));

// ---------------- helpers ----------------
__device__ __forceinline__ unsigned pk2(float a, float b){
  unsigned ua = __float_as_uint(a), ub = __float_as_uint(b);
  ua = (ua + 0x7fffu + ((ua >> 16) & 1u)) >> 16;
  ub = (ub + 0x7fffu + ((ub >> 16) & 1u)) >> 16;
  return ua | (ub << 16);
}
__device__ __forceinline__ unsigned short bf1(float a){
  unsigned ua = __float_as_uint(a);
  return (unsigned short)((ua + 0x7fffu + ((ua >> 16) & 1u)) >> 16);
}
__device__ __forceinline__ f32x4 mfma16(bf16x8 a, bf16x8 b, f32x4 c){
  return __builtin_amdgcn_mfma_f32_16x16x32_bf16(a, b, c, 0, 0, 0);
}
__device__ __forceinline__ void gl_lds16(const void* g, void* l){
  __builtin_amdgcn_global_load_lds(
      (const __attribute__((address_space(1))) unsigned int*)g,
      (__attribute__((address_space(3))) unsigned int*)l, 16, 0, 0);
}
// 128-byte-row tile (128 rows x 64 bf16), XOR-swizzled
__device__ __forceinline__ bf16x8 ldfrag128(const short* base, int row, int bo){
  const char* p = (const char*)base + row * 128 + (bo ^ ((row & 7) << 4));
  return *(const bf16x8*)p;
}
// 256-byte-row tile (128 rows x 128 bf16), XOR-swizzled
__device__ __forceinline__ bf16x8 ldfrag256(const short* base, int row, int bo){
  const char* p = (const char*)base + row * 256 + (bo ^ ((row & 7) << 4));
  return *(const bf16x8*)p;
}

// ---------------- K0: W1[:12544][:] -> Wt bf16 [128][12544] ----------------
__global__ __launch_bounds__(256) void k0_wt(const float* __restrict__ W1,
                                             unsigned short* __restrict__ Wt){
  __shared__ float tile[64][133];
  const int t  = threadIdx.x;
  const int k0 = blockIdx.x * 64;
  const int r0 = t >> 5;
  const int c4 = (t & 31) * 4;
#pragma unroll
  for (int i = 0; i < 8; ++i){
    int r = r0 + i * 8;
    float4 v = *(const float4*)(W1 + (long)(k0 + r) * NHID + c4);
    tile[r][c4+0] = v.x; tile[r][c4+1] = v.y; tile[r][c4+2] = v.z; tile[r][c4+3] = v.w;
  }
  __syncthreads();
  const int h  = t >> 1;
  const int kc = (t & 1) * 32;
  unsigned* dst = (unsigned*)(Wt + (long)h * DROI + k0 + kc);
#pragma unroll
  for (int kk = 0; kk < 32; kk += 2)
    dst[kk >> 1] = pk2(tile[kc + kk][h], tile[kc + kk + 1][h]);
}

// ---------------- K1: fused Gram + fv@W1, 8 waves role-split ----------------
// partial layout per (s, b*2+outw): 8192 uints, interleaved as
//   uint4 at [g*256 + slot], g=0..7, slot=0..255  (slot = (wave&3)*64 + lane)
//   uint4 g covers u = g*4 .. g*4+3, where u = m*16 + cb*2 + ip
template<int SK>
__global__ __launch_bounds__(512, 4) void k1_main(const float* __restrict__ fv,
    const unsigned short* __restrict__ Wt, unsigned* __restrict__ part){
  constexpr int KC = DROI / SK;
  constexpr int NT = KC / 64;
  __shared__ __align__(16) short lsA[2][8192];  // fv tile bf16 (16KB each)
  __shared__ __align__(16) short lsB[2][8192];  // Wt tile bf16
  const int tid  = threadIdx.x;
  const int wave = tid >> 6, lane = tid & 63;
  const int s = blockIdx.x, b = blockIdx.y;
  const int kbase = s * KC;

  f32x4 acc[2][8];
  {
    f32x4 z = {0.f, 0.f, 0.f, 0.f};
#pragma unroll
    for (int m = 0; m < 2; ++m)
#pragma unroll
      for (int c = 0; c < 8; ++c) acc[m][c] = z;
  }

  // fv staging: thread -> row r0, float cols colf..colf+15 (64B contiguous)
  const int r0   = tid >> 2;
  const int colf = (tid & 3) * 16;
  const float* fvt = fv + (long)(b * NDET + r0) * DROI + kbase + colf;
  const int hh  = lane >> 3;
  const int seg = (lane & 7) ^ hh;    // pre-swizzled source segment for gl_lds

  float4 stg[4];
  // ---- prologue: tile 0 ----
#pragma unroll
  for (int j = 0; j < 2; ++j){
    int call = wave * 2 + j;
    int h = call * 8 + hh;
    const char* g = (const char*)Wt + (long)h * (DROI * 2) + (long)kbase * 2 + seg * 16;
    gl_lds16(g, (char*)lsB[0] + call * 1024);
  }
#pragma unroll
  for (int i = 0; i < 4; ++i) stg[i] = *(const float4*)(fvt + i * 4);
  {
    char* basep = (char*)lsA[0];
    uint4 w0, w1;
    w0.x = pk2(stg[0].x, stg[0].y); w0.y = pk2(stg[0].z, stg[0].w);
    w0.z = pk2(stg[1].x, stg[1].y); w0.w = pk2(stg[1].z, stg[1].w);
    w1.x = pk2(stg[2].x, stg[2].y); w1.y = pk2(stg[2].z, stg[2].w);
    w1.z = pk2(stg[3].x, stg[3].y); w1.w = pk2(stg[3].z, stg[3].w);
    const int bo = colf * 2, sw = (r0 & 7) << 4;
    *(uint4*)(basep + r0 * 128 + (bo ^ sw)) = w0;
    *(uint4*)(basep + r0 * 128 + ((bo + 16) ^ sw)) = w1;
  }
  __syncthreads();

  const int outw = wave >> 2;         // 0 = Gram, 1 = XW1
  const int mq   = wave & 3;          // M-quarter (32 rows)
  const int lq   = lane & 15;
  int buf = 0;
  for (int t = 0; t < NT; ++t){
    const int nt = t + 1;
    if (nt < NT){
#pragma unroll
      for (int j = 0; j < 2; ++j){
        int call = wave * 2 + j;
        int h = call * 8 + hh;
        const char* g = (const char*)Wt + (long)h * (DROI * 2)
                      + (long)(kbase + nt * 64) * 2 + seg * 16;
        gl_lds16(g, (char*)lsB[buf ^ 1] + call * 1024);
      }
      const float* fp = fvt + nt * 64;
#pragma unroll
      for (int i = 0; i < 4; ++i) stg[i] = *(const float4*)(fp + i * 4);
    }
    const short* A  = lsA[buf];
    const short* Bs = outw ? lsB[buf] : lsA[buf];
#pragma unroll
    for (int kk = 0; kk < 2; ++kk){
      const int bo = kk * 64 + (lane >> 4) * 16;
      bf16x8 a0 = ldfrag128(A, mq * 32 + lq, bo);
      bf16x8 a1 = ldfrag128(A, mq * 32 + 16 + lq, bo);
#pragma unroll
      for (int cb = 0; cb < 8; ++cb){
        bf16x8 bb = ldfrag128(Bs, cb * 16 + lq, bo);
        acc[0][cb] = mfma16(a0, bb, acc[0][cb]);
        acc[1][cb] = mfma16(a1, bb, acc[1][cb]);
      }
    }
    if (nt < NT){
      char* basep = (char*)lsA[buf ^ 1];
      uint4 w0, w1;
      w0.x = pk2(stg[0].x, stg[0].y); w0.y = pk2(stg[0].z, stg[0].w);
      w0.z = pk2(stg[1].x, stg[1].y); w0.w = pk2(stg[1].z, stg[1].w);
      w1.x = pk2(stg[2].x, stg[2].y); w1.y = pk2(stg[2].z, stg[2].w);
      w1.z = pk2(stg[3].x, stg[3].y); w1.w = pk2(stg[3].z, stg[3].w);
      const int bo = colf * 2, sw = (r0 & 7) << 4;
      *(uint4*)(basep + r0 * 128 + (bo ^ sw)) = w0;
      *(uint4*)(basep + r0 * 128 + ((bo + 16) ^ sw)) = w1;
    }
    __syncthreads();
    buf ^= 1;
  }

  // ---- bf16 packed, fully-coalesced partial store ----
  const int slot = mq * 64 + lane;
  uint4* dst4 = (uint4*)(part + (((long)s * 32 + b * 2 + outw) * 8192));
#pragma unroll
  for (int g = 0; g < 8; ++g){
    const int m = g >> 2, cb0 = (g & 3) * 2;
    uint4 w;
    w.x = pk2(acc[m][cb0][0],     acc[m][cb0][1]);
    w.y = pk2(acc[m][cb0][2],     acc[m][cb0][3]);
    w.z = pk2(acc[m][cb0 + 1][0], acc[m][cb0 + 1][1]);
    w.w = pk2(acc[m][cb0 + 1][2], acc[m][cb0 + 1][3]);
    dst4[g * 256 + slot] = w;
  }
}

// ---------------- KR: split-K reduction (bf16 in, fp32 out, un-permute) ----
// outw=0 (Gram): canonical fin[R*128+C].  outw=1 (Y): transposed fin[C*128+R].
template<int SK>
__global__ __launch_bounds__(256) void k_reduce(const unsigned* __restrict__ part,
                                                float* __restrict__ fin){
  const int gq   = blockIdx.x * 256 + threadIdx.x;   // 0..262143
  const int q    = gq & 8191;
  const int bo2  = gq >> 13;                         // b*2 + outw
  float lo = 0.f, hi = 0.f;
#pragma unroll
  for (int s = 0; s < SK; ++s){
    unsigned v = part[(long)s * 262144 + (long)bo2 * 8192 + q];
    lo += __uint_as_float(v << 16);
    hi += __uint_as_float(v & 0xffff0000u);
  }
  const int g    = q >> 10;
  const int slot = (q & 1023) >> 2;
  const int w    = q & 3;
  const int m  = g >> 2;
  const int cb = (g & 3) * 2 + (w >> 1);
  const int ip = w & 1;
  const int mq = slot >> 6, lane = slot & 63;
  const int R = mq * 32 + m * 16 + (lane >> 4) * 4 + ip * 2;
  const int C = cb * 16 + (lane & 15);
  float* f = fin + (long)bo2 * 16384;
  if ((bo2 & 1) == 0){
    f[R * 128 + C] = lo;
    f[(R + 1) * 128 + C] = hi;
  } else {
    float2 v2; v2.x = lo; v2.y = hi;
    *(float2*)(f + C * 128 + R) = v2;
  }
}

// ---------------- K2: fused adjacency + 3 GEMMs + pool + logits ------------
__global__ __launch_bounds__(256, 1) void k2f(const float* __restrict__ fin,
    const float* __restrict__ ctr, const float* __restrict__ W1,
    const float* __restrict__ b1, const float* __restrict__ W2,
    const float* __restrict__ b2, const float* __restrict__ Wc,
    const float* __restrict__ bc, float* __restrict__ out){
  __shared__ __align__(16) short Ah[16384];   // 32KB: normalized adjacency (persistent)
  __shared__ __align__(16) short Bu[16384];   // 32KB: Yt -> H1 -> Tt
  __shared__ __align__(16) short Cu[16384];   // 32KB: W2t -> pool scratch
  __shared__ float sm2[256];                  // [0..127] invn, [128..255] dinv
  __shared__ float sctr[256];                 // ctr for this image
  const int b   = blockIdx.x;
  const int tid = threadIdx.x;
  const float* G  = fin + (long)b * 32768;
  const float* Yt = G + 16384;                // stored TRANSPOSED: Yt[c][k]

  // (1) ctr cache + inverse norms from Gram diagonal
  sctr[tid] = ctr[b * 256 + tid];
  if (tid < 128){
    float g = G[tid * 129];
    sm2[tid] = 1.0f / fmaxf(sqrtf(g), 1e-12f);
  }
  __syncthreads();

  // (2) adjacency masks + degrees
  const int   i   = tid >> 1;
  const int   jb  = (tid & 1) * 64;
  const float invni = sm2[i];
  const float cxi = sctr[2 * i], cyi = sctr[2 * i + 1];
  unsigned m0 = 0, m1 = 0;
  int degloc = 0;
  for (int j4 = 0; j4 < 64; j4 += 4){
    float4 g4 = *(const float4*)(G + i * 128 + jb + j4);
    float gg[4] = {g4.x, g4.y, g4.z, g4.w};
#pragma unroll
    for (int u = 0; u < 4; ++u){
      int j = jb + j4 + u;
      float cs = gg[u] * invni * sm2[j];
      float dx = cxi - sctr[2 * j];
      float dy = cyi - sctr[2 * j + 1];
      float d2 = dx * dx + dy * dy;
      if (d2 < 2500.0f || cs > 0.8f){
        int bp = j4 + u;
        if (bp < 32) m0 |= (1u << bp); else m1 |= (1u << (bp - 32));
        ++degloc;
      }
    }
  }
  if (i >= jb && i < jb + 64) ++degloc;       // self loop
  int degfull = degloc + __shfl_xor(degloc, 1);
  if ((tid & 1) == 0) sm2[128 + i] = rsqrtf((float)degfull);
  __syncthreads();

  // (3) write normalized adjacency into Ah (swizzled bf16)
  {
    const float dinvi = sm2[128 + i];
    char* AhB = (char*)Ah;
    for (int jp = 0; jp < 64; jp += 2){
      int j0 = jb + jp, j1 = j0 + 1;
      float a0 = (((jp   < 32) ? ((m0 >> jp)       & 1u) : ((m1 >> (jp - 32))     & 1u)) ? 1.f : 0.f);
      float a1 = (((jp+1 < 32) ? ((m0 >> (jp + 1)) & 1u) : ((m1 >> (jp + 1 - 32)) & 1u)) ? 1.f : 0.f);
      if (i == j0) a0 += 1.f;
      if (i == j1) a1 += 1.f;
      float v0 = dinvi * a0 * sm2[128 + j0];
      float v1 = dinvi * a1 * sm2[128 + j1];
      int bo = j0 * 2;
      *(unsigned*)(AhB + i * 256 + (bo ^ ((i & 7) << 4))) = pk2(v0, v1);
    }
  }

  // (4) stage W2t[c][k] into Cu
  {
    const int c     = tid & 127;
    const int khalf = tid >> 7;
    char* WB = (char*)Cu;
    for (int k8 = khalf * 64; k8 < khalf * 64 + 64; k8 += 8){
      float f[8];
#pragma unroll
      for (int u = 0; u < 8; ++u) f[u] = W2[(k8 + u) * 128 + c];
      uint4 w;
      w.x = pk2(f[0], f[1]); w.y = pk2(f[2], f[3]);
      w.z = pk2(f[4], f[5]); w.w = pk2(f[6], f[7]);
      int bo = k8 * 2;
      *(uint4*)(WB + c * 256 + (bo ^ ((c & 7) << 4))) = w;
    }
  }
  // (5) stage Yt tile from transposed fin (coalesced float4 rows) + ctr tail
  {
    const int cr = tid >> 1;
    const int kh = (tid & 1) * 64;
    const float w1a = W1[(long)12544 * NHID + cr];
    const float w1b = W1[(long)12545 * NHID + cr];
    const float* Yr = Yt + cr * 128 + kh;
    char* YtB = (char*)Bu;
    for (int k8 = 0; k8 < 64; k8 += 8){
      float4 va = *(const float4*)(Yr + k8);
      float4 vb = *(const float4*)(Yr + k8 + 4);
      float f[8] = {va.x, va.y, va.z, va.w, vb.x, vb.y, vb.z, vb.w};
#pragma unroll
      for (int u = 0; u < 8; ++u){
        int k = kh + k8 + u;
        f[u] += sctr[2 * k] * w1a + sctr[2 * k + 1] * w1b;
      }
      uint4 w;
      w.x = pk2(f[0], f[1]); w.y = pk2(f[2], f[3]);
      w.z = pk2(f[4], f[5]); w.w = pk2(f[6], f[7]);
      int bo = (kh + k8) * 2;
      *(uint4*)(YtB + cr * 256 + (bo ^ ((cr & 7) << 4))) = w;
    }
  }
  __syncthreads();

  const int wave = tid >> 6, lane = tid & 63;
  const int lq = lane & 15;
  f32x4 acc[2][8];
  f32x4 z4 = {0.f, 0.f, 0.f, 0.f};

  // (6) GEMM1: H1 = relu(Ah @ Yt + b1)
#pragma unroll
  for (int r = 0; r < 2; ++r)
#pragma unroll
    for (int cc = 0; cc < 8; ++cc) acc[r][cc] = z4;
#pragma unroll
  for (int ks = 0; ks < 4; ++ks){
    const int bo = ks * 64 + (lane >> 4) * 16;
    bf16x8 a0 = ldfrag256(Ah, (wave*2+0)*16 + lq, bo);
    bf16x8 a1 = ldfrag256(Ah, (wave*2+1)*16 + lq, bo);
#pragma unroll
    for (int cb = 0; cb < 8; ++cb){
      bf16x8 bb = ldfrag256(Bu, cb*16 + lq, bo);
      acc[0][cb] = mfma16(a0, bb, acc[0][cb]);
      acc[1][cb] = mfma16(a1, bb, acc[1][cb]);
    }
  }
  __syncthreads();   // all Yt reads done
  // (7) scatter H1 (bf16, swizzled) into Bu
  {
    char* BuB = (char*)Bu;
#pragma unroll
    for (int rb = 0; rb < 2; ++rb){
      const int R0 = wave*32 + rb*16 + (lane >> 4)*4;
#pragma unroll
      for (int cb = 0; cb < 8; ++cb){
        const int C = cb*16 + lq;
        const float bb1 = b1[C];
#pragma unroll
        for (int u = 0; u < 4; ++u){
          float v = fmaxf(acc[rb][cb][u] + bb1, 0.f);
          int row = R0 + u;
          *(unsigned short*)(BuB + row * 256 + ((C * 2) ^ ((row & 7) << 4))) = bf1(v);
        }
      }
    }
  }
  __syncthreads();

  // (8) GEMM2: T = H1 @ W2t
#pragma unroll
  for (int r = 0; r < 2; ++r)
#pragma unroll
    for (int cc = 0; cc < 8; ++cc) acc[r][cc] = z4;
#pragma unroll
  for (int ks = 0; ks < 4; ++ks){
    const int bo = ks * 64 + (lane >> 4) * 16;
    bf16x8 a0 = ldfrag256(Bu, (wave*2+0)*16 + lq, bo);
    bf16x8 a1 = ldfrag256(Bu, (wave*2+1)*16 + lq, bo);
#pragma unroll
    for (int cb = 0; cb < 8; ++cb){
      bf16x8 bb = ldfrag256(Cu, cb*16 + lq, bo);
      acc[0][cb] = mfma16(a0, bb, acc[0][cb]);
      acc[1][cb] = mfma16(a1, bb, acc[1][cb]);
    }
  }
  __syncthreads();   // all H1 reads done
  // (9) scatter T^T into Bu: Tt[c][k]
  {
    char* BuB = (char*)Bu;
#pragma unroll
    for (int rb = 0; rb < 2; ++rb){
      const int R0 = wave*32 + rb*16 + (lane >> 4)*4;
#pragma unroll
      for (int cb = 0; cb < 8; ++cb){
        const int C = cb*16 + lq;
#pragma unroll
        for (int u = 0; u < 4; ++u){
          int k = R0 + u;
          *(unsigned short*)(BuB + C * 256 + ((k * 2) ^ ((C & 7) << 4))) = bf1(acc[rb][cb][u]);
        }
      }
    }
  }
  __syncthreads();

  // (10) GEMM3: C2 = Ah @ Tt; relu(+b2); mean pool; logits
#pragma unroll
  for (int r = 0; r < 2; ++r)
#pragma unroll
    for (int cc = 0; cc < 8; ++cc) acc[r][cc] = z4;
#pragma unroll
  for (int ks = 0; ks < 4; ++ks){
    const int bo = ks * 64 + (lane >> 4) * 16;
    bf16x8 a0 = ldfrag256(Ah, (wave*2+0)*16 + lq, bo);
    bf16x8 a1 = ldfrag256(Ah, (wave*2+1)*16 + lq, bo);
#pragma unroll
    for (int cb = 0; cb < 8; ++cb){
      bf16x8 bb = ldfrag256(Bu, cb*16 + lq, bo);
      acc[0][cb] = mfma16(a0, bb, acc[0][cb]);
      acc[1][cb] = mfma16(a1, bb, acc[1][cb]);
    }
  }
  float colp[8];
#pragma unroll
  for (int cb = 0; cb < 8; ++cb){
    const int C = cb*16 + lq;
    const float bb2 = b2[C];
    float sum = 0.f;
#pragma unroll
    for (int rb = 0; rb < 2; ++rb)
#pragma unroll
      for (int u = 0; u < 4; ++u)
        sum += fmaxf(acc[rb][cb][u] + bb2, 0.f);
    colp[cb] = sum;
  }
#pragma unroll
  for (int cb = 0; cb < 8; ++cb){
    float v = colp[cb];
    v += __shfl_xor(v, 16);
    v += __shfl_xor(v, 32);
    colp[cb] = v;
  }
  __syncthreads();                    // GEMM reads done; Cu free
  float* hgp = (float*)Cu;            // [4][128]
  if ((lane >> 4) == 0){
#pragma unroll
    for (int cb = 0; cb < 8; ++cb)
      hgp[wave * 128 + cb * 16 + lane] = colp[cb];
  }
  __syncthreads();
  float* hg = hgp + 512;
  if (tid < 128)
    hg[tid] = (hgp[tid] + hgp[128 + tid] + hgp[256 + tid] + hgp[384 + tid]) * (1.0f / 128.0f);
  __syncthreads();
  if (tid < 22){
    float a2 = bc[tid];
    for (int h = 0; h < 128; ++h) a2 += hg[h] * Wc[h * 22 + tid];
    out[b * 22 + tid] = a2;
  }
}

// ---------------- launch ----------------
extern "C" void kernel_launch(void* const* d_in, const int* in_sizes, int n_in,
                              void* d_out, int out_size, void* d_ws, size_t ws_size,
                              hipStream_t stream){
  (void)in_sizes; (void)n_in; (void)out_size;
  const float* fv  = (const float*)d_in[0];
  const float* ctr = (const float*)d_in[1];
  const float* W1  = (const float*)d_in[2];
  const float* b1  = (const float*)d_in[3];
  const float* W2  = (const float*)d_in[4];
  const float* b2  = (const float*)d_in[5];
  const float* Wc  = (const float*)d_in[6];
  const float* bc  = (const float*)d_in[7];
  char* ws = (char*)d_ws;
  float* out = (float*)d_out;

  const unsigned long SZ_WT  = (unsigned long)NHID * DROI * 2;   // 3,211,264
  const unsigned long SZ_FIN = (unsigned long)BIMG * 2 * 16384 * 4;

  // part per split: 32 * 8192 uints = 1 MB
  const unsigned long need28 = SZ_WT + 28UL * 1048576UL + SZ_FIN;
  const bool big = (ws_size >= need28);
  const int SK = big ? 28 : 14;

  unsigned short* Wt   = (unsigned short*)(ws);
  unsigned*       part = (unsigned*)(ws + SZ_WT);
  float*          fin  = (float*)(ws + SZ_WT + (unsigned long)SK * 1048576UL);

  k0_wt<<<dim3(DROI / 64), dim3(256), 0, stream>>>(W1, Wt);
  if (big){
    k1_main<28><<<dim3(28, BIMG), dim3(512), 0, stream>>>(fv, Wt, part);
    k_reduce<28><<<dim3(1024), dim3(256), 0, stream>>>(part, fin);
  } else {
    k1_main<14><<<dim3(14, BIMG), dim3(512), 0, stream>>>(fv, Wt, part);
    k_reduce<14><<<dim3(1024), dim3(256), 0, stream>>>(part, fin);
  }
  k2f<<<dim3(BIMG), dim3(256), 0, stream>>>(fin, ctr, W1, b1, W2, b2, Wc, bc, out);
}

// Round 4
// 62.161 us; speedup vs baseline: 1.4729x; 1.0513x over previous
//
#include <hip/hip_runtime.h>
#include <stdint.h>

#define DROI   12544
#define BIMG   16
#define NDET   128
#define NHID   128

typedef __bf16 bf16x8 __attribute__((ext_vector_type(8)));
typedef float  f32x4  __attribute__((ext_vector_type(4)));

// ---------------- helpers ----------------
__device__ __forceinline__ unsigned pk2(float a, float b){
  unsigned ua = __float_as_uint(a), ub = __float_as_uint(b);
  ua = (ua + 0x7fffu + ((ua >> 16) & 1u)) >> 16;
  ub = (ub + 0x7fffu + ((ub >> 16) & 1u)) >> 16;
  return ua | (ub << 16);
}
__device__ __forceinline__ unsigned short bf1(float a){
  unsigned ua = __float_as_uint(a);
  return (unsigned short)((ua + 0x7fffu + ((ua >> 16) & 1u)) >> 16);
}
__device__ __forceinline__ f32x4 mfma16(bf16x8 a, bf16x8 b, f32x4 c){
  return __builtin_amdgcn_mfma_f32_16x16x32_bf16(a, b, c, 0, 0, 0);
}
__device__ __forceinline__ void gl_lds16(const void* g, void* l){
  __builtin_amdgcn_global_load_lds(
      (const __attribute__((address_space(1))) unsigned int*)g,
      (__attribute__((address_space(3))) unsigned int*)l, 16, 0, 0);
}
// 128-byte-row tile (128 rows x 64 bf16), XOR-swizzled
__device__ __forceinline__ bf16x8 ldfrag128(const short* base, int row, int bo){
  const char* p = (const char*)base + row * 128 + (bo ^ ((row & 7) << 4));
  return *(const bf16x8*)p;
}
// 256-byte-row tile (128 rows x 128 bf16), XOR-swizzled
__device__ __forceinline__ bf16x8 ldfrag256(const short* base, int row, int bo){
  const char* p = (const char*)base + row * 256 + (bo ^ ((row & 7) << 4));
  return *(const bf16x8*)p;
}

// ---------------- K0: W1[:12544][:] -> Wt bf16 [128][12544] ----------------
__global__ __launch_bounds__(256) void k0_wt(const float* __restrict__ W1,
                                             unsigned short* __restrict__ Wt){
  __shared__ float tile[64][133];
  const int t  = threadIdx.x;
  const int k0 = blockIdx.x * 64;
  const int r0 = t >> 5;
  const int c4 = (t & 31) * 4;
#pragma unroll
  for (int i = 0; i < 8; ++i){
    int r = r0 + i * 8;
    float4 v = *(const float4*)(W1 + (long)(k0 + r) * NHID + c4);
    tile[r][c4+0] = v.x; tile[r][c4+1] = v.y; tile[r][c4+2] = v.z; tile[r][c4+3] = v.w;
  }
  __syncthreads();
  const int h  = t >> 1;
  const int kc = (t & 1) * 32;
  unsigned* dst = (unsigned*)(Wt + (long)h * DROI + k0 + kc);
#pragma unroll
  for (int kk = 0; kk < 32; kk += 2)
    dst[kk >> 1] = pk2(tile[kc + kk][h], tile[kc + kk + 1][h]);
}

// ---------------- K1: fused Gram + fv@W1, depth-2 counted-vmcnt pipeline ---
// partial layout per (s, b*2+outw): 8192 uints (bf16 pairs), as in k_reduce.
template<int SK>
__global__ __launch_bounds__(512, 4) void k1_main(const float* __restrict__ fv,
    const unsigned short* __restrict__ Wt, unsigned* __restrict__ part){
  constexpr int KC = DROI / SK;
  constexpr int NT = KC / 64;
  static_assert(NT >= 3, "pipeline needs >=3 tiles");
  __shared__ __align__(16) short lsA[2][8192];   // fv tile bf16 (16KB each)
  __shared__ __align__(16) short lsB[3][8192];   // Wt tile bf16, 3-deep rotation
  const int tid  = threadIdx.x;
  const int wave = tid >> 6, lane = tid & 63;

  // XCD-aware swizzle (nwg divisible by 8): contiguous s-ranges per XCD
  const int nwg  = SK * BIMG;
  const int cpx  = nwg >> 3;
  const int orig = blockIdx.x;
  const int wg   = (orig & 7) * cpx + (orig >> 3);
  const int s = wg >> 4;
  const int b = wg & 15;
  const int kbase = s * KC;

  f32x4 acc[2][8];
  {
    f32x4 z = {0.f, 0.f, 0.f, 0.f};
#pragma unroll
    for (int m = 0; m < 2; ++m)
#pragma unroll
      for (int c = 0; c < 8; ++c) acc[m][c] = z;
  }

  // fv staging: row r0 = tid>>2; thread loads 4x float4 at cols colf + i*16
  const int r0   = tid >> 2;
  const int colf = (tid & 3) * 4;
  const int sw   = (r0 & 7) << 4;
  const float* fvt = fv + (long)(b * NDET + r0) * DROI + kbase + colf;
  const int hh  = lane >> 3;
  const int seg = (lane & 7) ^ hh;    // pre-swizzled source segment for gl_lds

  const int outw = wave >> 2;         // 0 = Gram, 1 = XW1
  const int mq   = wave & 3;          // M-quarter (32 rows)
  const int lq   = lane & 15;

  float4 stg[4];

  auto issueF = [&](int t){
    const float* fp = fvt + t * 64;
#pragma unroll
    for (int i = 0; i < 4; ++i) stg[i] = *(const float4*)(fp + i * 16);
  };
  auto issueG = [&](int t, int bufi){
#pragma unroll
    for (int j = 0; j < 2; ++j){
      int call = wave * 2 + j;
      int h = call * 8 + hh;
      const char* g = (const char*)Wt + (long)h * (DROI * 2)
                    + (long)(kbase + t * 64) * 2 + seg * 16;
      gl_lds16(g, (char*)lsB[bufi] + call * 1024);
    }
  };
  auto writeA = [&](int abuf){
    char* basep = (char*)lsA[abuf];
#pragma unroll
    for (int i = 0; i < 4; ++i){
      uint2 w; w.x = pk2(stg[i].x, stg[i].y); w.y = pk2(stg[i].z, stg[i].w);
      int bo = (colf + i * 16) * 2;
      *(uint2*)(basep + r0 * 128 + (bo ^ sw)) = w;
    }
  };

  // ---- prologue: A(0), B(0), B(1) ----
  issueF(0);
  __builtin_amdgcn_sched_barrier(0);
  issueG(0, 0);
  issueG(1, 1);
  __builtin_amdgcn_sched_barrier(0);
  writeA(0);                                        // auto-wait drains F(0)
  asm volatile("s_waitcnt vmcnt(2)" ::: "memory");  // B(0) done; B(1) in flight
  asm volatile("s_waitcnt lgkmcnt(0)" ::: "memory");
  __builtin_amdgcn_sched_barrier(0);
  __builtin_amdgcn_s_barrier();
  __builtin_amdgcn_sched_barrier(0);

#pragma unroll
  for (int t = 0; t < NT; ++t){
    if (t + 1 < NT) issueF(t + 1);
    __builtin_amdgcn_sched_barrier(0);
    if (t + 2 < NT) issueG(t + 2, (t + 2) % 3);
    __builtin_amdgcn_sched_barrier(0);
    // compute tile t (B(t) guaranteed complete; A(t) published at last barrier)
    {
      const short* A  = lsA[t & 1];
      const short* Bs = outw ? lsB[t % 3] : lsA[t & 1];
#pragma unroll
      for (int kk = 0; kk < 2; ++kk){
        const int bo = kk * 64 + (lane >> 4) * 16;
        bf16x8 a0 = ldfrag128(A, mq * 32 + lq, bo);
        bf16x8 a1 = ldfrag128(A, mq * 32 + 16 + lq, bo);
#pragma unroll
        for (int cb = 0; cb < 8; ++cb){
          bf16x8 bb = ldfrag128(Bs, cb * 16 + lq, bo);
          acc[0][cb] = mfma16(a0, bb, acc[0][cb]);
          acc[1][cb] = mfma16(a1, bb, acc[1][cb]);
        }
      }
    }
    __builtin_amdgcn_sched_barrier(0);
    if (t + 1 < NT){
      writeA((t + 1) & 1);   // compiler auto-emits counted vmcnt for F(t+1),
                             // leaving B(t+2) in flight across the barrier
      asm volatile("s_waitcnt lgkmcnt(0)" ::: "memory");
      __builtin_amdgcn_sched_barrier(0);
      __builtin_amdgcn_s_barrier();
      __builtin_amdgcn_sched_barrier(0);
    }
  }

  // ---- bf16 packed, fully-coalesced partial store ----
  const int slot = mq * 64 + lane;
  uint4* dst4 = (uint4*)(part + (((long)s * 32 + b * 2 + outw) * 8192));
#pragma unroll
  for (int g = 0; g < 8; ++g){
    const int m = g >> 2, cb0 = (g & 3) * 2;
    uint4 w;
    w.x = pk2(acc[m][cb0][0],     acc[m][cb0][1]);
    w.y = pk2(acc[m][cb0][2],     acc[m][cb0][3]);
    w.z = pk2(acc[m][cb0 + 1][0], acc[m][cb0 + 1][1]);
    w.w = pk2(acc[m][cb0 + 1][2], acc[m][cb0 + 1][3]);
    dst4[g * 256 + slot] = w;
  }
}

// ---------------- KR: split-K reduce, LDS transpose, coalesced both sides --
// outw=0 (Gram): canonical fin[R*128+C].  outw=1 (Y): transposed fin[C*128+R].
template<int SK>
__global__ __launch_bounds__(256) void k_reduce(const unsigned* __restrict__ part,
                                                float* __restrict__ fin){
  __shared__ float tile[16][33];
  const int tid = threadIdx.x;
  const int B   = blockIdx.x;            // 0..1023
  const int bo2 = B >> 5;                // b*2 + outw
  const int q   = (B & 31) * 256 + tid;  // within-part uint index
  float lo = 0.f, hi = 0.f;
  const unsigned* p = part + (long)bo2 * 8192 + q;
#pragma unroll
  for (int s = 0; s < SK; ++s){
    unsigned v = p[(long)s * 262144];
    lo += __uint_as_float(v << 16);
    hi += __uint_as_float(v & 0xffff0000u);
  }
  // decode q -> (R,C) of the k1 accumulator layout
  const int g    = q >> 10;              // uniform per block
  const int slot = (q & 1023) >> 2;
  const int w    = q & 3;
  const int m  = g >> 2;
  const int cb1 = w >> 1;                // cb low bit
  const int ip = w & 1;
  const int mq = slot >> 6, lane = slot & 63;
  const int r   = ((lane >> 4) << 2) + (ip << 1);   // 0..14 even
  const int col = (cb1 << 4) + (lane & 15);         // 0..31
  tile[r][col]     = lo;
  tile[r + 1][col] = hi;
  __syncthreads();
  const int Rbase = mq * 32 + m * 16;    // uniform per block
  const int Cbase = (g & 3) * 32;        // uniform per block
  float* f = fin + (long)bo2 * 16384;
  if ((bo2 & 1) == 0){
#pragma unroll
    for (int k = 0; k < 2; ++k){
      int idx = k * 256 + tid;
      int rr = idx >> 5, cc = idx & 31;
      f[(Rbase + rr) * 128 + Cbase + cc] = tile[rr][cc];
    }
  } else {
#pragma unroll
    for (int k = 0; k < 2; ++k){
      int idx = k * 256 + tid;
      int cc = idx >> 4, rr = idx & 15;
      f[(Cbase + cc) * 128 + Rbase + rr] = tile[rr][cc];
    }
  }
}

// ---------------- K2: fused adjacency + 3 GEMMs + pool + logits ------------
__global__ __launch_bounds__(256, 1) void k2f(const float* __restrict__ fin,
    const float* __restrict__ ctr, const float* __restrict__ W1,
    const float* __restrict__ b1, const float* __restrict__ W2,
    const float* __restrict__ b2, const float* __restrict__ Wc,
    const float* __restrict__ bc, float* __restrict__ out){
  __shared__ __align__(16) short Ah[16384];   // normalized adjacency (persistent)
  __shared__ __align__(16) short Bu[16384];   // Yt -> H1 -> Tt
  __shared__ __align__(16) short Cu[16384];   // W2t -> pool scratch
  __shared__ float sm2[256];
  __shared__ float sctr[256];
  const int b   = blockIdx.x;
  const int tid = threadIdx.x;
  const float* G  = fin + (long)b * 32768;
  const float* Yt = G + 16384;                // stored TRANSPOSED: Yt[c][k]

  sctr[tid] = ctr[b * 256 + tid];
  if (tid < 128){
    float g = G[tid * 129];
    sm2[tid] = 1.0f / fmaxf(sqrtf(g), 1e-12f);
  }
  __syncthreads();

  const int   i   = tid >> 1;
  const int   jb  = (tid & 1) * 64;
  const float invni = sm2[i];
  const float cxi = sctr[2 * i], cyi = sctr[2 * i + 1];
  unsigned m0 = 0, m1 = 0;
  int degloc = 0;
  for (int j4 = 0; j4 < 64; j4 += 4){
    float4 g4 = *(const float4*)(G + i * 128 + jb + j4);
    float gg[4] = {g4.x, g4.y, g4.z, g4.w};
#pragma unroll
    for (int u = 0; u < 4; ++u){
      int j = jb + j4 + u;
      float cs = gg[u] * invni * sm2[j];
      float dx = cxi - sctr[2 * j];
      float dy = cyi - sctr[2 * j + 1];
      float d2 = dx * dx + dy * dy;
      if (d2 < 2500.0f || cs > 0.8f){
        int bp = j4 + u;
        if (bp < 32) m0 |= (1u << bp); else m1 |= (1u << (bp - 32));
        ++degloc;
      }
    }
  }
  if (i >= jb && i < jb + 64) ++degloc;
  int degfull = degloc + __shfl_xor(degloc, 1);
  if ((tid & 1) == 0) sm2[128 + i] = rsqrtf((float)degfull);
  __syncthreads();

  {
    const float dinvi = sm2[128 + i];
    char* AhB = (char*)Ah;
    for (int jp = 0; jp < 64; jp += 2){
      int j0 = jb + jp, j1 = j0 + 1;
      float a0 = (((jp   < 32) ? ((m0 >> jp)       & 1u) : ((m1 >> (jp - 32))     & 1u)) ? 1.f : 0.f);
      float a1 = (((jp+1 < 32) ? ((m0 >> (jp + 1)) & 1u) : ((m1 >> (jp + 1 - 32)) & 1u)) ? 1.f : 0.f);
      if (i == j0) a0 += 1.f;
      if (i == j1) a1 += 1.f;
      float v0 = dinvi * a0 * sm2[128 + j0];
      float v1 = dinvi * a1 * sm2[128 + j1];
      int bo = j0 * 2;
      *(unsigned*)(AhB + i * 256 + (bo ^ ((i & 7) << 4))) = pk2(v0, v1);
    }
  }

  {
    const int c     = tid & 127;
    const int khalf = tid >> 7;
    char* WB = (char*)Cu;
    for (int k8 = khalf * 64; k8 < khalf * 64 + 64; k8 += 8){
      float f[8];
#pragma unroll
      for (int u = 0; u < 8; ++u) f[u] = W2[(k8 + u) * 128 + c];
      uint4 w;
      w.x = pk2(f[0], f[1]); w.y = pk2(f[2], f[3]);
      w.z = pk2(f[4], f[5]); w.w = pk2(f[6], f[7]);
      int bo = k8 * 2;
      *(uint4*)(WB + c * 256 + (bo ^ ((c & 7) << 4))) = w;
    }
  }
  {
    const int cr = tid >> 1;
    const int kh = (tid & 1) * 64;
    const float w1a = W1[(long)12544 * NHID + cr];
    const float w1b = W1[(long)12545 * NHID + cr];
    const float* Yr = Yt + cr * 128 + kh;
    char* YtB = (char*)Bu;
    for (int k8 = 0; k8 < 64; k8 += 8){
      float4 va = *(const float4*)(Yr + k8);
      float4 vb = *(const float4*)(Yr + k8 + 4);
      float f[8] = {va.x, va.y, va.z, va.w, vb.x, vb.y, vb.z, vb.w};
#pragma unroll
      for (int u = 0; u < 8; ++u){
        int k = kh + k8 + u;
        f[u] += sctr[2 * k] * w1a + sctr[2 * k + 1] * w1b;
      }
      uint4 w;
      w.x = pk2(f[0], f[1]); w.y = pk2(f[2], f[3]);
      w.z = pk2(f[4], f[5]); w.w = pk2(f[6], f[7]);
      int bo = (kh + k8) * 2;
      *(uint4*)(YtB + cr * 256 + (bo ^ ((cr & 7) << 4))) = w;
    }
  }
  __syncthreads();

  const int wave = tid >> 6, lane = tid & 63;
  const int lq = lane & 15;
  f32x4 acc[2][8];
  f32x4 z4 = {0.f, 0.f, 0.f, 0.f};

  // GEMM1: H1 = relu(Ah @ Yt + b1)
#pragma unroll
  for (int r = 0; r < 2; ++r)
#pragma unroll
    for (int cc = 0; cc < 8; ++cc) acc[r][cc] = z4;
#pragma unroll
  for (int ks = 0; ks < 4; ++ks){
    const int bo = ks * 64 + (lane >> 4) * 16;
    bf16x8 a0 = ldfrag256(Ah, (wave*2+0)*16 + lq, bo);
    bf16x8 a1 = ldfrag256(Ah, (wave*2+1)*16 + lq, bo);
#pragma unroll
    for (int cb = 0; cb < 8; ++cb){
      bf16x8 bb = ldfrag256(Bu, cb*16 + lq, bo);
      acc[0][cb] = mfma16(a0, bb, acc[0][cb]);
      acc[1][cb] = mfma16(a1, bb, acc[1][cb]);
    }
  }
  __syncthreads();
  {
    char* BuB = (char*)Bu;
#pragma unroll
    for (int rb = 0; rb < 2; ++rb){
      const int R0 = wave*32 + rb*16 + (lane >> 4)*4;
#pragma unroll
      for (int cb = 0; cb < 8; ++cb){
        const int C = cb*16 + lq;
        const float bb1 = b1[C];
#pragma unroll
        for (int u = 0; u < 4; ++u){
          float v = fmaxf(acc[rb][cb][u] + bb1, 0.f);
          int row = R0 + u;
          *(unsigned short*)(BuB + row * 256 + ((C * 2) ^ ((row & 7) << 4))) = bf1(v);
        }
      }
    }
  }
  __syncthreads();

  // GEMM2: T = H1 @ W2t
#pragma unroll
  for (int r = 0; r < 2; ++r)
#pragma unroll
    for (int cc = 0; cc < 8; ++cc) acc[r][cc] = z4;
#pragma unroll
  for (int ks = 0; ks < 4; ++ks){
    const int bo = ks * 64 + (lane >> 4) * 16;
    bf16x8 a0 = ldfrag256(Bu, (wave*2+0)*16 + lq, bo);
    bf16x8 a1 = ldfrag256(Bu, (wave*2+1)*16 + lq, bo);
#pragma unroll
    for (int cb = 0; cb < 8; ++cb){
      bf16x8 bb = ldfrag256(Cu, cb*16 + lq, bo);
      acc[0][cb] = mfma16(a0, bb, acc[0][cb]);
      acc[1][cb] = mfma16(a1, bb, acc[1][cb]);
    }
  }
  __syncthreads();
  {
    char* BuB = (char*)Bu;
#pragma unroll
    for (int rb = 0; rb < 2; ++rb){
      const int R0 = wave*32 + rb*16 + (lane >> 4)*4;
#pragma unroll
      for (int cb = 0; cb < 8; ++cb){
        const int C = cb*16 + lq;
#pragma unroll
        for (int u = 0; u < 4; ++u){
          int k = R0 + u;
          *(unsigned short*)(BuB + C * 256 + ((k * 2) ^ ((C & 7) << 4))) = bf1(acc[rb][cb][u]);
        }
      }
    }
  }
  __syncthreads();

  // GEMM3: C2 = Ah @ Tt; relu(+b2); mean pool; logits
#pragma unroll
  for (int r = 0; r < 2; ++r)
#pragma unroll
    for (int cc = 0; cc < 8; ++cc) acc[r][cc] = z4;
#pragma unroll
  for (int ks = 0; ks < 4; ++ks){
    const int bo = ks * 64 + (lane >> 4) * 16;
    bf16x8 a0 = ldfrag256(Ah, (wave*2+0)*16 + lq, bo);
    bf16x8 a1 = ldfrag256(Ah, (wave*2+1)*16 + lq, bo);
#pragma unroll
    for (int cb = 0; cb < 8; ++cb){
      bf16x8 bb = ldfrag256(Bu, cb*16 + lq, bo);
      acc[0][cb] = mfma16(a0, bb, acc[0][cb]);
      acc[1][cb] = mfma16(a1, bb, acc[1][cb]);
    }
  }
  float colp[8];
#pragma unroll
  for (int cb = 0; cb < 8; ++cb){
    const int C = cb*16 + lq;
    const float bb2 = b2[C];
    float sum = 0.f;
#pragma unroll
    for (int rb = 0; rb < 2; ++rb)
#pragma unroll
      for (int u = 0; u < 4; ++u)
        sum += fmaxf(acc[rb][cb][u] + bb2, 0.f);
    colp[cb] = sum;
  }
#pragma unroll
  for (int cb = 0; cb < 8; ++cb){
    float v = colp[cb];
    v += __shfl_xor(v, 16);
    v += __shfl_xor(v, 32);
    colp[cb] = v;
  }
  __syncthreads();
  float* hgp = (float*)Cu;
  if ((lane >> 4) == 0){
#pragma unroll
    for (int cb = 0; cb < 8; ++cb)
      hgp[wave * 128 + cb * 16 + lane] = colp[cb];
  }
  __syncthreads();
  float* hg = hgp + 512;
  if (tid < 128)
    hg[tid] = (hgp[tid] + hgp[128 + tid] + hgp[256 + tid] + hgp[384 + tid]) * (1.0f / 128.0f);
  __syncthreads();
  if (tid < 22){
    float a2 = bc[tid];
    for (int h = 0; h < 128; ++h) a2 += hg[h] * Wc[h * 22 + tid];
    out[b * 22 + tid] = a2;
  }
}

// ---------------- launch ----------------
extern "C" void kernel_launch(void* const* d_in, const int* in_sizes, int n_in,
                              void* d_out, int out_size, void* d_ws, size_t ws_size,
                              hipStream_t stream){
  (void)in_sizes; (void)n_in; (void)out_size;
  const float* fv  = (const float*)d_in[0];
  const float* ctr = (const float*)d_in[1];
  const float* W1  = (const float*)d_in[2];
  const float* b1  = (const float*)d_in[3];
  const float* W2  = (const float*)d_in[4];
  const float* b2  = (const float*)d_in[5];
  const float* Wc  = (const float*)d_in[6];
  const float* bc  = (const float*)d_in[7];
  char* ws = (char*)d_ws;
  float* out = (float*)d_out;

  const unsigned long SZ_WT  = (unsigned long)NHID * DROI * 2;   // 3,211,264
  const unsigned long SZ_FIN = (unsigned long)BIMG * 2 * 16384 * 4;

  const unsigned long need28 = SZ_WT + 28UL * 1048576UL + SZ_FIN;
  const bool big = (ws_size >= need28);
  const int SK = big ? 28 : 14;

  unsigned short* Wt   = (unsigned short*)(ws);
  unsigned*       part = (unsigned*)(ws + SZ_WT);
  float*          fin  = (float*)(ws + SZ_WT + (unsigned long)SK * 1048576UL);

  k0_wt<<<dim3(DROI / 64), dim3(256), 0, stream>>>(W1, Wt);
  if (big){
    k1_main<28><<<dim3(28 * BIMG), dim3(512), 0, stream>>>(fv, Wt, part);
    k_reduce<28><<<dim3(1024), dim3(256), 0, stream>>>(part, fin);
  } else {
    k1_main<14><<<dim3(14 * BIMG), dim3(512), 0, stream>>>(fv, Wt, part);
    k_reduce<14><<<dim3(1024), dim3(256), 0, stream>>>(part, fin);
  }
  k2f<<<dim3(BIMG), dim3(256), 0, stream>>>(fin, ctr, W1, b1, W2, b2, Wc, bc, out);
}

// Round 7
// 58.752 us; speedup vs baseline: 1.5584x; 1.0580x over previous
//
#include <hip/hip_runtime.h>
#include <stdint.h>

#define DROI   12544
#define BIMG   16
#define NDET   128
#define NHID   128

typedef __bf16 bf16x8 __attribute__((ext_vector_type(8)));
typedef float  f32x4  __attribute__((ext_vector_type(4)));

// ---------------- helpers ----------------
__device__ __forceinline__ unsigned pk2(float a, float b){
  unsigned ua = __float_as_uint(a), ub = __float_as_uint(b);
  ua = (ua + 0x7fffu + ((ua >> 16) & 1u)) >> 16;
  ub = (ub + 0x7fffu + ((ub >> 16) & 1u)) >> 16;
  return ua | (ub << 16);
}
__device__ __forceinline__ unsigned short bf1(float a){
  unsigned ua = __float_as_uint(a);
  return (unsigned short)((ua + 0x7fffu + ((ua >> 16) & 1u)) >> 16);
}
__device__ __forceinline__ f32x4 mfma16(bf16x8 a, bf16x8 b, f32x4 c){
  return __builtin_amdgcn_mfma_f32_16x16x32_bf16(a, b, c, 0, 0, 0);
}
__device__ __forceinline__ void gl_lds16(const void* g, void* l){
  __builtin_amdgcn_global_load_lds(
      (const __attribute__((address_space(1))) unsigned int*)g,
      (__attribute__((address_space(3))) unsigned int*)l, 16, 0, 0);
}
// 128-byte-row tile (128 rows x 64 bf16), XOR-swizzled
__device__ __forceinline__ bf16x8 ldfrag128(const short* base, int row, int bo){
  const char* p = (const char*)base + row * 128 + (bo ^ ((row & 7) << 4));
  return *(const bf16x8*)p;
}
// 256-byte-row tile (128 rows x 128 bf16), XOR-swizzled
__device__ __forceinline__ bf16x8 ldfrag256(const short* base, int row, int bo){
  const char* p = (const char*)base + row * 256 + (bo ^ ((row & 7) << 4));
  return *(const bf16x8*)p;
}

// ---------------- K0: W1[:12544][:] -> Wt bf16 [128][12544] ----------------
__global__ __launch_bounds__(256) void k0_wt(const float* __restrict__ W1,
                                             unsigned short* __restrict__ Wt){
  __shared__ float tile[64][133];
  const int t  = threadIdx.x;
  const int k0 = blockIdx.x * 64;
  const int r0 = t >> 5;
  const int c4 = (t & 31) * 4;
#pragma unroll
  for (int i = 0; i < 8; ++i){
    int r = r0 + i * 8;
    float4 v = *(const float4*)(W1 + (long)(k0 + r) * NHID + c4);
    tile[r][c4+0] = v.x; tile[r][c4+1] = v.y; tile[r][c4+2] = v.z; tile[r][c4+3] = v.w;
  }
  __syncthreads();
  const int h  = t >> 1;
  const int kc = (t & 1) * 32;
  unsigned* dst = (unsigned*)(Wt + (long)h * DROI + k0 + kc);
#pragma unroll
  for (int kk = 0; kk < 32; kk += 2)
    dst[kk >> 1] = pk2(tile[kc + kk][h], tile[kc + kk + 1][h]);
}

// ---------------- K1: fused Gram + fv@W1, depth-1F/depth-2G pipeline -------
template<int SK>
__global__ __launch_bounds__(512, 4) void k1_main(const float* __restrict__ fv,
    const unsigned short* __restrict__ Wt, unsigned* __restrict__ part){
  constexpr int KC = DROI / SK;
  constexpr int NT = KC / 64;
  static_assert(NT >= 3, "pipeline needs >=3 tiles");
  __shared__ __align__(16) short lsA[2][8192];   // fv tile bf16 (16KB each)
  __shared__ __align__(16) short lsB[3][8192];   // Wt tile bf16, 3-deep rotation
  const int tid  = threadIdx.x;
  const int wave = tid >> 6, lane = tid & 63;

  // XCD-aware swizzle (nwg divisible by 8)
  const int nwg  = SK * BIMG;
  const int cpx  = nwg >> 3;
  const int orig = blockIdx.x;
  const int wg   = (orig & 7) * cpx + (orig >> 3);
  const int s = wg >> 4;
  const int b = wg & 15;
  const int kbase = s * KC;

  f32x4 acc[2][8];
  {
    f32x4 z = {0.f, 0.f, 0.f, 0.f};
#pragma unroll
    for (int m = 0; m < 2; ++m)
#pragma unroll
      for (int c = 0; c < 8; ++c) acc[m][c] = z;
  }

  const int r0   = tid >> 2;
  const int colf = (tid & 3) * 4;
  const int sw   = (r0 & 7) << 4;
  const float* fvt = fv + (long)(b * NDET + r0) * DROI + kbase + colf;
  const int hh  = lane >> 3;
  const int seg = (lane & 7) ^ hh;

  const int outw = wave >> 2;         // 0 = Gram, 1 = XW1
  const int mq   = wave & 3;          // M-quarter (32 rows)
  const int lq   = lane & 15;

  float4 stg[4];

  auto issueF = [&](int t){
    const float* fp = fvt + t * 64;
#pragma unroll
    for (int i = 0; i < 4; ++i) stg[i] = *(const float4*)(fp + i * 16);
  };
  auto issueG = [&](int t, int bufi){
#pragma unroll
    for (int j = 0; j < 2; ++j){
      int call = wave * 2 + j;
      int h = call * 8 + hh;
      const char* g = (const char*)Wt + (long)h * (DROI * 2)
                    + (long)(kbase + t * 64) * 2 + seg * 16;
      gl_lds16(g, (char*)lsB[bufi] + call * 1024);
    }
  };
  auto writeA = [&](int abuf){
    char* basep = (char*)lsA[abuf];
#pragma unroll
    for (int i = 0; i < 4; ++i){
      uint2 w; w.x = pk2(stg[i].x, stg[i].y); w.y = pk2(stg[i].z, stg[i].w);
      int bo = (colf + i * 16) * 2;
      *(uint2*)(basep + r0 * 128 + (bo ^ sw)) = w;
    }
  };

  // ---- prologue: A(0), B(0), B(1) ----
  issueF(0);
  __builtin_amdgcn_sched_barrier(0);
  issueG(0, 0);
  issueG(1, 1);
  __builtin_amdgcn_sched_barrier(0);
  writeA(0);                                        // auto-wait drains F0
  asm volatile("s_waitcnt vmcnt(2)" ::: "memory");  // drains G0; leaves G1
  asm volatile("s_waitcnt lgkmcnt(0)" ::: "memory");
  __builtin_amdgcn_sched_barrier(0);
  __builtin_amdgcn_s_barrier();
  __builtin_amdgcn_sched_barrier(0);

#pragma unroll
  for (int t = 0; t < NT; ++t){
    if (t + 1 < NT) issueF(t + 1);
    __builtin_amdgcn_sched_barrier(0);
    if (t + 2 < NT) issueG(t + 2, (t + 2) % 3);
    __builtin_amdgcn_sched_barrier(0);
    {
      const short* A  = lsA[t & 1];
      const short* Bs = outw ? lsB[t % 3] : lsA[t & 1];
#pragma unroll
      for (int kk = 0; kk < 2; ++kk){
        const int bo = kk * 64 + (lane >> 4) * 16;
        bf16x8 a0 = ldfrag128(A, mq * 32 + lq, bo);
        bf16x8 a1 = ldfrag128(A, mq * 32 + 16 + lq, bo);
#pragma unroll
        for (int cb = 0; cb < 8; ++cb){
          bf16x8 bb = ldfrag128(Bs, cb * 16 + lq, bo);
          acc[0][cb] = mfma16(a0, bb, acc[0][cb]);
          acc[1][cb] = mfma16(a1, bb, acc[1][cb]);
        }
      }
    }
    __builtin_amdgcn_sched_barrier(0);
    if (t + 1 < NT){
      writeA((t + 1) & 1);   // auto-wait drains F(t+1); FIFO also drains G(t+1)
      asm volatile("s_waitcnt lgkmcnt(0)" ::: "memory");
      __builtin_amdgcn_sched_barrier(0);
      __builtin_amdgcn_s_barrier();
      __builtin_amdgcn_sched_barrier(0);
    }
  }

  // ---- bf16 packed, fully-coalesced partial store ----
  const int slot = mq * 64 + lane;
  uint4* dst4 = (uint4*)(part + (((long)s * 32 + b * 2 + outw) * 8192));
#pragma unroll
  for (int g = 0; g < 8; ++g){
    const int m = g >> 2, cb0 = (g & 3) * 2;
    uint4 w;
    w.x = pk2(acc[m][cb0][0],     acc[m][cb0][1]);
    w.y = pk2(acc[m][cb0][2],     acc[m][cb0][3]);
    w.z = pk2(acc[m][cb0 + 1][0], acc[m][cb0 + 1][1]);
    w.w = pk2(acc[m][cb0 + 1][2], acc[m][cb0 + 1][3]);
    dst4[g * 256 + slot] = w;
  }
}

// ---------------- KR: split-K reduce, LDS transpose, coalesced both sides --
template<int SK>
__global__ __launch_bounds__(256) void k_reduce(const unsigned* __restrict__ part,
                                                float* __restrict__ fin){
  __shared__ float tile[16][33];
  const int tid = threadIdx.x;
  const int B   = blockIdx.x;            // 0..1023
  const int bo2 = B >> 5;                // b*2 + outw
  const int q   = (B & 31) * 256 + tid;  // within-part uint index
  float lo = 0.f, hi = 0.f;
  const unsigned* p = part + (long)bo2 * 8192 + q;
#pragma unroll
  for (int s = 0; s < SK; ++s){
    unsigned v = p[(long)s * 262144];
    lo += __uint_as_float(v << 16);
    hi += __uint_as_float(v & 0xffff0000u);
  }
  const int g    = q >> 10;
  const int slot = (q & 1023) >> 2;
  const int w    = q & 3;
  const int m  = g >> 2;
  const int cb1 = w >> 1;
  const int ip = w & 1;
  const int mq = slot >> 6, lane = slot & 63;
  const int r   = ((lane >> 4) << 2) + (ip << 1);
  const int col = (cb1 << 4) + (lane & 15);
  tile[r][col]     = lo;
  tile[r + 1][col] = hi;
  __syncthreads();
  const int Rbase = mq * 32 + m * 16;
  const int Cbase = (g & 3) * 32;
  float* f = fin + (long)bo2 * 16384;
  if ((bo2 & 1) == 0){
#pragma unroll
    for (int k = 0; k < 2; ++k){
      int idx = k * 256 + tid;
      int rr = idx >> 5, cc = idx & 31;
      f[(Rbase + rr) * 128 + Cbase + cc] = tile[rr][cc];
    }
  } else {
#pragma unroll
    for (int k = 0; k < 2; ++k){
      int idx = k * 256 + tid;
      int cc = idx >> 4, rr = idx & 15;
      f[(Cbase + cc) * 128 + Rbase + rr] = tile[rr][cc];
    }
  }
}

// ---------------- K2: fused adjacency + 3 GEMMs + pool + logits, 512 thr ---
__global__ __launch_bounds__(512, 1) void k2f(const float* __restrict__ fin,
    const float* __restrict__ ctr, const float* __restrict__ W1,
    const float* __restrict__ b1, const float* __restrict__ W2,
    const float* __restrict__ b2, const float* __restrict__ Wc,
    const float* __restrict__ bc, float* __restrict__ out){
  __shared__ __align__(16) short Ah[16384];   // normalized adjacency (persistent)
  __shared__ __align__(16) short Bu[16384];   // Yt -> H1 -> Tt
  __shared__ __align__(16) short Cu[16384];   // W2t -> pool scratch
  __shared__ float sm2[256];
  __shared__ float sctr[256];
  const int b   = blockIdx.x;
  const int tid = threadIdx.x;
  const float* G  = fin + (long)b * 32768;
  const float* Yt = G + 16384;                // stored TRANSPOSED: Yt[c][k]

  if (tid < 256) sctr[tid] = ctr[b * 256 + tid];
  if (tid < 128){
    float g = G[tid * 129];
    sm2[tid] = 1.0f / fmaxf(sqrtf(g), 1e-12f);
  }
  __syncthreads();

  // adjacency: thread (i, j-quarter of 32)
  const int   i   = tid >> 2;
  const int   jq  = (tid & 3) * 32;
  const float invni = sm2[i];
  const float cxi = sctr[2 * i], cyi = sctr[2 * i + 1];
  unsigned m0 = 0;
  int degloc = 0;
  for (int j4 = 0; j4 < 32; j4 += 4){
    float4 g4 = *(const float4*)(G + i * 128 + jq + j4);
    float gg[4] = {g4.x, g4.y, g4.z, g4.w};
#pragma unroll
    for (int u = 0; u < 4; ++u){
      int j = jq + j4 + u;
      float cs = gg[u] * invni * sm2[j];
      float dx = cxi - sctr[2 * j];
      float dy = cyi - sctr[2 * j + 1];
      float d2 = dx * dx + dy * dy;
      if (d2 < 2500.0f || cs > 0.8f){
        m0 |= (1u << (j4 + u));
        ++degloc;
      }
    }
  }
  if (i >= jq && i < jq + 32) ++degloc;       // self loop (exactly one quarter holds i)
  degloc += __shfl_xor(degloc, 1);
  degloc += __shfl_xor(degloc, 2);
  if ((tid & 3) == 0) sm2[128 + i] = rsqrtf((float)degloc);
  __syncthreads();

  {
    const float dinvi = sm2[128 + i];
    char* AhB = (char*)Ah;
#pragma unroll
    for (int jp = 0; jp < 32; jp += 2){
      int j0 = jq + jp, j1 = j0 + 1;
      float a0 = ((m0 >> jp)       & 1u) ? 1.f : 0.f;
      float a1 = ((m0 >> (jp + 1)) & 1u) ? 1.f : 0.f;
      if (i == j0) a0 += 1.f;
      if (i == j1) a1 += 1.f;
      float v0 = dinvi * a0 * sm2[128 + j0];
      float v1 = dinvi * a1 * sm2[128 + j1];
      int bo = j0 * 2;
      *(unsigned*)(AhB + i * 256 + (bo ^ ((i & 7) << 4))) = pk2(v0, v1);
    }
  }

  // stage W2t[c][k] into Cu (4 threads per col, 32 k each)
  {
    const int c  = tid & 127;
    const int kq = (tid >> 7) * 32;
    char* WB = (char*)Cu;
#pragma unroll
    for (int k8 = kq; k8 < kq + 32; k8 += 8){
      float f[8];
#pragma unroll
      for (int u = 0; u < 8; ++u) f[u] = W2[(k8 + u) * 128 + c];
      uint4 w;
      w.x = pk2(f[0], f[1]); w.y = pk2(f[2], f[3]);
      w.z = pk2(f[4], f[5]); w.w = pk2(f[6], f[7]);
      int bo = k8 * 2;
      *(uint4*)(WB + c * 256 + (bo ^ ((c & 7) << 4))) = w;
    }
  }
  // stage Yt tile from transposed fin + ctr tail (4 threads per row, 32 k)
  {
    const int cr = tid >> 2;
    const int kq = (tid & 3) * 32;
    const float w1a = W1[(long)12544 * NHID + cr];
    const float w1b = W1[(long)12545 * NHID + cr];
    const float* Yr = Yt + cr * 128 + kq;
    char* YtB = (char*)Bu;
#pragma unroll
    for (int k8 = 0; k8 < 32; k8 += 8){
      float4 va = *(const float4*)(Yr + k8);
      float4 vb = *(const float4*)(Yr + k8 + 4);
      float f[8] = {va.x, va.y, va.z, va.w, vb.x, vb.y, vb.z, vb.w};
#pragma unroll
      for (int u = 0; u < 8; ++u){
        int k = kq + k8 + u;
        f[u] += sctr[2 * k] * w1a + sctr[2 * k + 1] * w1b;
      }
      uint4 w;
      w.x = pk2(f[0], f[1]); w.y = pk2(f[2], f[3]);
      w.z = pk2(f[4], f[5]); w.w = pk2(f[6], f[7]);
      int bo = (kq + k8) * 2;
      *(uint4*)(YtB + cr * 256 + (bo ^ ((cr & 7) << 4))) = w;
    }
  }
  __syncthreads();

  const int wave = tid >> 6, lane = tid & 63;
  const int lq = lane & 15;
  f32x4 acc[8];
  f32x4 z4 = {0.f, 0.f, 0.f, 0.f};

  // GEMM1: H1 = relu(Ah @ Yt + b1) — wave owns 16 rows
#pragma unroll
  for (int cc = 0; cc < 8; ++cc) acc[cc] = z4;
#pragma unroll
  for (int ks = 0; ks < 4; ++ks){
    const int bo = ks * 64 + (lane >> 4) * 16;
    bf16x8 a0 = ldfrag256(Ah, wave * 16 + lq, bo);
#pragma unroll
    for (int cb = 0; cb < 8; ++cb){
      bf16x8 bb = ldfrag256(Bu, cb * 16 + lq, bo);
      acc[cb] = mfma16(a0, bb, acc[cb]);
    }
  }
  __syncthreads();
  {
    char* BuB = (char*)Bu;
    const int R0 = wave * 16 + (lane >> 4) * 4;
#pragma unroll
    for (int cb = 0; cb < 8; ++cb){
      const int C = cb * 16 + lq;
      const float bb1 = b1[C];
#pragma unroll
      for (int u = 0; u < 4; ++u){
        float v = fmaxf(acc[cb][u] + bb1, 0.f);
        int row = R0 + u;
        *(unsigned short*)(BuB + row * 256 + ((C * 2) ^ ((row & 7) << 4))) = bf1(v);
      }
    }
  }
  __syncthreads();

  // GEMM2: T = H1 @ W2t
#pragma unroll
  for (int cc = 0; cc < 8; ++cc) acc[cc] = z4;
#pragma unroll
  for (int ks = 0; ks < 4; ++ks){
    const int bo = ks * 64 + (lane >> 4) * 16;
    bf16x8 a0 = ldfrag256(Bu, wave * 16 + lq, bo);
#pragma unroll
    for (int cb = 0; cb < 8; ++cb){
      bf16x8 bb = ldfrag256(Cu, cb * 16 + lq, bo);
      acc[cb] = mfma16(a0, bb, acc[cb]);
    }
  }
  __syncthreads();
  {
    char* BuB = (char*)Bu;
    const int R0 = wave * 16 + (lane >> 4) * 4;
#pragma unroll
    for (int cb = 0; cb < 8; ++cb){
      const int C = cb * 16 + lq;
#pragma unroll
      for (int u = 0; u < 4; u += 2){
        int k = R0 + u;   // even
        unsigned w = pk2(acc[cb][u], acc[cb][u + 1]);
        *(unsigned*)(BuB + C * 256 + ((k * 2) ^ ((C & 7) << 4))) = w;
      }
    }
  }
  __syncthreads();

  // GEMM3: C2 = Ah @ Tt; relu(+b2); mean pool; logits
#pragma unroll
  for (int cc = 0; cc < 8; ++cc) acc[cc] = z4;
#pragma unroll
  for (int ks = 0; ks < 4; ++ks){
    const int bo = ks * 64 + (lane >> 4) * 16;
    bf16x8 a0 = ldfrag256(Ah, wave * 16 + lq, bo);
#pragma unroll
    for (int cb = 0; cb < 8; ++cb){
      bf16x8 bb = ldfrag256(Bu, cb * 16 + lq, bo);
      acc[cb] = mfma16(a0, bb, acc[cb]);
    }
  }
  float colp[8];
#pragma unroll
  for (int cb = 0; cb < 8; ++cb){
    const float bb2 = b2[cb * 16 + lq];
    float sum = 0.f;
#pragma unroll
    for (int u = 0; u < 4; ++u)
      sum += fmaxf(acc[cb][u] + bb2, 0.f);
    colp[cb] = sum;
  }
#pragma unroll
  for (int cb = 0; cb < 8; ++cb){
    float v = colp[cb];
    v += __shfl_xor(v, 16);
    v += __shfl_xor(v, 32);
    colp[cb] = v;
  }
  float* hgp = (float*)Cu;            // [8][128] partial col sums (Cu dead after GEMM2)
  if ((lane >> 4) == 0){
#pragma unroll
    for (int cb = 0; cb < 8; ++cb)
      hgp[wave * 128 + cb * 16 + lane] = colp[cb];
  }
  __syncthreads();
  float* hg = hgp + 1024;
  if (tid < 128){
    float s = 0.f;
#pragma unroll
    for (int w = 0; w < 8; ++w) s += hgp[w * 128 + tid];
    hg[tid] = s * (1.0f / 128.0f);
  }
  __syncthreads();
  if (tid < 22){
    float a2 = bc[tid];
    for (int h = 0; h < 128; ++h) a2 += hg[h] * Wc[h * 22 + tid];
    out[b * 22 + tid] = a2;
  }
}

// ---------------- launch ----------------
extern "C" void kernel_launch(void* const* d_in, const int* in_sizes, int n_in,
                              void* d_out, int out_size, void* d_ws, size_t ws_size,
                              hipStream_t stream){
  (void)in_sizes; (void)n_in; (void)out_size;
  const float* fv  = (const float*)d_in[0];
  const float* ctr = (const float*)d_in[1];
  const float* W1  = (const float*)d_in[2];
  const float* b1  = (const float*)d_in[3];
  const float* W2  = (const float*)d_in[4];
  const float* b2  = (const float*)d_in[5];
  const float* Wc  = (const float*)d_in[6];
  const float* bc  = (const float*)d_in[7];
  char* ws = (char*)d_ws;
  float* out = (float*)d_out;

  const unsigned long SZ_WT  = (unsigned long)NHID * DROI * 2;   // 3,211,264
  const unsigned long SZ_FIN = (unsigned long)BIMG * 2 * 16384 * 4;

  const unsigned long need28 = SZ_WT + 28UL * 1048576UL + SZ_FIN;
  const bool big = (ws_size >= need28);
  const int SK = big ? 28 : 14;

  unsigned short* Wt   = (unsigned short*)(ws);
  unsigned*       part = (unsigned*)(ws + SZ_WT);
  float*          fin  = (float*)(ws + SZ_WT + (unsigned long)SK * 1048576UL);

  k0_wt<<<dim3(DROI / 64), dim3(256), 0, stream>>>(W1, Wt);
  if (big){
    k1_main<28><<<dim3(28 * BIMG), dim3(512), 0, stream>>>(fv, Wt, part);
    k_reduce<28><<<dim3(1024), dim3(256), 0, stream>>>(part, fin);
  } else {
    k1_main<14><<<dim3(14 * BIMG), dim3(512), 0, stream>>>(fv, Wt, part);
    k_reduce<14><<<dim3(1024), dim3(256), 0, stream>>>(part, fin);
  }
  k2f<<<dim3(BIMG), dim3(512), 0, stream>>>(fin, ctr, W1, b1, W2, b2, Wc, bc, out);
}